// Round 1
// baseline (878.685 us; speedup 1.0000x reference)
//
#include <hip/hip_runtime.h>

static constexpr int NN  = 20000;
static constexpr int NE  = 320000;
static constexpr int NHH = 4;
static constexpr int DK  = 64;
static constexpr int NTY = 4;
static constexpr int NRL = 8;

typedef short bf16x8 __attribute__((ext_vector_type(8)));
typedef float f32x4  __attribute__((ext_vector_type(4)));
typedef unsigned short u16x4 __attribute__((ext_vector_type(4)));

__device__ __forceinline__ unsigned short f2bf(float f) {
  unsigned u = __float_as_uint(f);
  u += 0x7fffu + ((u >> 16) & 1u);
  return (unsigned short)(u >> 16);
}
__device__ __forceinline__ float bf2f(unsigned short b) {
  return __uint_as_float(((unsigned)b) << 16);
}
__device__ __forceinline__ unsigned enc_f(float s) {
  unsigned u = __float_as_uint(s);
  return (u & 0x80000000u) ? ~u : (u | 0x80000000u);
}
__device__ __forceinline__ float dec_f(unsigned u) {
  return (u & 0x80000000u) ? __uint_as_float(u & 0x7fffffffu)
                           : __uint_as_float(~u);
}
__device__ __forceinline__ f32x4 mfma16(bf16x8 a, bf16x8 b, f32x4 c) {
  return __builtin_amdgcn_mfma_f32_16x16x32_bf16(a, b, c, 0, 0, 0);
}

// ---------------- prep ----------------
__global__ void k_zero(unsigned* p, int n) {
  int i = blockIdx.x * 256 + threadIdx.x;
  if (i < n) p[i] = 0;
}
__global__ void k_copy(const int* s, int* d, int n) {
  int i = blockIdx.x * 256 + threadIdx.x;
  if (i < n) d[i] = s[i];
}
__global__ void k_cast(const float* in, unsigned short* out, int n) {
  int i = blockIdx.x * 256 + threadIdx.x;
  if (i < n) out[i] = f2bf(in[i]);
}
// Wt[t][j][i] = W{k|q|v}[t][i][j]  (B^T layout), j in [0,768)
__global__ void k_prep_wkqv(const float* Wk, const float* Wq, const float* Wv,
                            unsigned short* Wt) {
  int j = blockIdx.x % 768, t = blockIdx.x / 768, i = threadIdx.x;
  const float* src; int c;
  if (j < 256)      { src = Wk; c = j; }
  else if (j < 512) { src = Wq; c = j - 256; }
  else              { src = Wv; c = j - 512; }
  Wt[(t * 768 + j) * 256 + i] = f2bf(src[(t * 256 + i) * 256 + c]);
}
__global__ void k_prep_a(const float* Wa, unsigned short* At) {
  int j = blockIdx.x % 256, t = blockIdx.x / 256, i = threadIdx.x;
  At[(t * 256 + j) * 256 + i] = f2bf(Wa[(t * 256 + i) * 256 + j]);
}
// relXT[rh][e][d] = rel[rh][d][e]
__global__ void k_prep_rel(const float* att, const float* msg,
                           unsigned short* relAT, unsigned short* relMT) {
  int idx = blockIdx.x * 256 + threadIdx.x;
  if (idx >= NRL * NHH * DK * DK) return;
  int rh = idx >> 12, e = (idx >> 6) & 63, d = idx & 63;
  relAT[idx] = f2bf(att[rh * 4096 + d * 64 + e]);
  relMT[idx] = f2bf(msg[rh * 4096 + d * 64 + e]);
}

// ---------------- bucketing / CSR ----------------
__global__ void k_count(const int* key, int* cnt, int n) {
  int i = blockIdx.x * 256 + threadIdx.x;
  if (i < n) atomicAdd(&cnt[key[i]], 1);
}
__global__ void k_scan4(const int* cnt, int* off, int* cur) {
  if (threadIdx.x == 0 && blockIdx.x == 0) {
    int s = 0;
    for (int t = 0; t < NTY; ++t) { off[t] = s; cur[t] = s; s += cnt[t]; }
    off[NTY] = s;
  }
}
__global__ void k_scatter(const int* key, int* cur, int* perm, int n) {
  int i = blockIdx.x * 256 + threadIdx.x;
  if (i < n) { int p = atomicAdd(&cur[key[i]], 1); perm[p] = i; }
}
__global__ void k_scan_big(const int* cnt, int* off, int n) {
  __shared__ int part[1024];
  int tid = threadIdx.x;
  int chunk = (n + 1023) / 1024;
  int start = tid * chunk;
  int stop = min(start + chunk, n);
  int s = 0;
  for (int i = start; i < stop; ++i) s += cnt[i];
  part[tid] = s;
  __syncthreads();
  for (int d = 1; d < 1024; d <<= 1) {
    int t = (tid >= d) ? part[tid - d] : 0;
    __syncthreads();
    part[tid] += t;
    __syncthreads();
  }
  int run = part[tid] - s;  // exclusive prefix
  for (int i = start; i < stop; ++i) { off[i] = run; run += cnt[i]; }
  if (tid == 1023) off[n] = run;
}

// ---------------- K1: typed K/Q/V projection (gathered MFMA GEMM) ----------------
__global__ __launch_bounds__(256) void k_gemm_kqv(
    const unsigned short* __restrict__ hb, const unsigned short* __restrict__ Wt,
    const int* __restrict__ nperm, const int* __restrict__ toff,
    float* __restrict__ kf, unsigned short* __restrict__ qb,
    unsigned short* __restrict__ vb) {
  int wave = threadIdx.x >> 6, lane = threadIdx.x & 63;
  int t = blockIdx.y;
  int tile = blockIdx.x * 4 + wave;           // < 1250*48
  int tm = tile / 48, tn = tile % 48;
  int base = toff[t], cnt = toff[t + 1] - base;
  if (tm * 16 >= cnt) return;
  int lr = lane & 15, kq = lane >> 4;
  int arow = tm * 16 + lr;
  int node = nperm[base + (arow < cnt ? arow : cnt - 1)];
  const unsigned short* aptr = hb + node * 256 + kq * 8;
  const unsigned short* bptr = Wt + ((t * 768 + tn * 16 + lr) * 256) + kq * 8;
  f32x4 acc = {0.f, 0.f, 0.f, 0.f};
#pragma unroll
  for (int kk = 0; kk < 256; kk += 32) {
    bf16x8 a = *(const bf16x8*)(aptr + kk);
    bf16x8 b = *(const bf16x8*)(bptr + kk);
    acc = mfma16(a, b, acc);
  }
  int ccol = tn * 16 + lr;
#pragma unroll
  for (int i = 0; i < 4; ++i) {
    int crow = tm * 16 + kq * 4 + i;
    if (crow < cnt) {
      int nd = nperm[base + crow];
      float v = acc[i];
      if (ccol < 256)       kf[nd * 256 + ccol] = v;
      else if (ccol < 512)  qb[nd * 256 + (ccol - 256)] = f2bf(v);
      else                  vb[nd * 256 + (ccol - 512)] = f2bf(v);
    }
  }
}

// ---------------- K2: relation transforms q_att / v_msg ----------------
__global__ __launch_bounds__(256) void k_rel_gemm(
    const unsigned short* __restrict__ qb, const unsigned short* __restrict__ vb,
    const unsigned short* __restrict__ relAT, const unsigned short* __restrict__ relMT,
    unsigned short* __restrict__ q_att, unsigned short* __restrict__ v_msg) {
  int wave = threadIdx.x >> 6, lane = threadIdx.x & 63;
  int tile = blockIdx.x * 4 + wave;           // < 160000
  int tn = tile & 3, rh = (tile >> 2) & 31, tm = tile >> 7;
  int io = blockIdx.y;
  const unsigned short* X = io ? vb : qb;
  const unsigned short* B = (io ? relMT : relAT) + rh * 4096;
  unsigned short* O = io ? v_msg : q_att;
  int r = rh >> 2, h = rh & 3;
  int lr = lane & 15, kq = lane >> 4;
  const unsigned short* aptr = X + (tm * 16 + lr) * 256 + h * 64 + kq * 8;
  const unsigned short* bptr = B + (tn * 16 + lr) * 64 + kq * 8;
  f32x4 acc = {0.f, 0.f, 0.f, 0.f};
  acc = mfma16(*(const bf16x8*)aptr, *(const bf16x8*)bptr, acc);
  acc = mfma16(*(const bf16x8*)(aptr + 32), *(const bf16x8*)(bptr + 32), acc);
  int col = tn * 16 + lr;
#pragma unroll
  for (int i = 0; i < 4; ++i) {
    int n = tm * 16 + kq * 4 + i;
    O[((long)r * NN + n) * 256 + h * 64 + col] = f2bf(acc[i]);
  }
}

// ---------------- K3: edge scores + segment max ----------------
__global__ __launch_bounds__(256) void k_score(
    const unsigned short* __restrict__ q_att, const float* __restrict__ kf,
    const int* __restrict__ etype, const int* __restrict__ row_idx,
    const int* __restrict__ col_idx, const float* __restrict__ pri,
    float* __restrict__ score, unsigned* __restrict__ mmax) {
  int lane = threadIdx.x & 63;
  int e = blockIdx.x * 4 + (threadIdx.x >> 6);
  int r = etype[e], src = row_idx[e], dst = col_idx[e];
  int h = lane >> 4, i = lane & 15;
  const unsigned short* qa = q_att + ((long)r * NN + dst) * 256 + h * 64 + i * 4;
  const float* kp = kf + src * 256 + h * 64 + i * 4;
  u16x4 qv = *(const u16x4*)qa;
  f32x4 kv = *(const f32x4*)kp;
  float s = bf2f(qv[0]) * kv[0] + bf2f(qv[1]) * kv[1] +
            bf2f(qv[2]) * kv[2] + bf2f(qv[3]) * kv[3];
  s += __shfl_xor(s, 1);
  s += __shfl_xor(s, 2);
  s += __shfl_xor(s, 4);
  s += __shfl_xor(s, 8);
  if (i == 0) {
    s = s * pri[r * 4 + h] * 0.125f;
    score[e * 4 + h] = s;
    atomicMax(&mmax[dst * 4 + h], enc_f(s));
  }
}

// ---------------- K4: exp + denom ----------------
__global__ void k_exden(const int* __restrict__ col_idx, const unsigned* __restrict__ mmax,
                        float* __restrict__ score, float* __restrict__ denom) {
  int idx = blockIdx.x * 256 + threadIdx.x;
  if (idx >= NE * 4) return;
  int e = idx >> 2, h = idx & 3;
  int dst = col_idx[e];
  float m = dec_f(mmax[dst * 4 + h]);
  float ex = __expf(score[idx] - m);
  score[idx] = ex;
  atomicAdd(&denom[dst * 4 + h], ex);
}

// ---------------- K5: CSR aggregation ----------------
__global__ __launch_bounds__(256) void k_agg(
    const int* __restrict__ eoff, const int* __restrict__ eperm,
    const int* __restrict__ etype, const int* __restrict__ row_idx,
    const float* __restrict__ ex, const float* __restrict__ denom,
    const unsigned short* __restrict__ v_msg, unsigned short* __restrict__ agg) {
  int w = blockIdx.x * 4 + (threadIdx.x >> 6);  // (dst, head)
  int dst = w >> 2, h = w & 3, d = threadIdx.x & 63;
  int b = eoff[dst], en = eoff[dst + 1];
  float acc = 0.f;
  float dinv = (en > b) ? 1.f / denom[dst * 4 + h] : 0.f;
  for (int j = b; j < en; ++j) {
    int e = eperm[j];
    int r = etype[e], src = row_idx[e];
    float alpha = ex[e * 4 + h] * dinv;
    acc += alpha * bf2f(v_msg[((long)r * NN + src) * 256 + h * 64 + d]);
  }
  agg[dst * 256 + h * 64 + d] = f2bf(acc);
}

// ---------------- K6: final typed projection + sigmoid(skip) ----------------
__global__ __launch_bounds__(256) void k_gemm_out(
    const unsigned short* __restrict__ agg, const unsigned short* __restrict__ At,
    const int* __restrict__ nperm, const int* __restrict__ toff,
    const float* __restrict__ skip, float* __restrict__ out) {
  int wave = threadIdx.x >> 6, lane = threadIdx.x & 63;
  int t = blockIdx.y;
  int tile = blockIdx.x * 4 + wave;  // < 1250*16
  int tm = tile / 16, tn = tile % 16;
  int base = toff[t], cnt = toff[t + 1] - base;
  if (tm * 16 >= cnt) return;
  int lr = lane & 15, kq = lane >> 4;
  int arow = tm * 16 + lr;
  int node = nperm[base + (arow < cnt ? arow : cnt - 1)];
  const unsigned short* aptr = agg + node * 256 + kq * 8;
  const unsigned short* bptr = At + (t * 256 + tn * 16 + lr) * 256 + kq * 8;
  f32x4 acc = {0.f, 0.f, 0.f, 0.f};
#pragma unroll
  for (int kk = 0; kk < 256; kk += 32)
    acc = mfma16(*(const bf16x8*)(aptr + kk), *(const bf16x8*)(bptr + kk), acc);
  float sg = 1.f / (1.f + __expf(-skip[t]));
  int ccol = tn * 16 + lr;
#pragma unroll
  for (int i = 0; i < 4; ++i) {
    int crow = tm * 16 + kq * 4 + i;
    if (crow < cnt) {
      int nd = nperm[base + crow];
      out[nd * 256 + ccol] = acc[i] * sg;
    }
  }
}

extern "C" void kernel_launch(void* const* d_in, const int* in_sizes, int n_in,
                              void* d_out, int out_size, void* d_ws, size_t ws_size,
                              hipStream_t stream) {
  (void)in_sizes; (void)n_in; (void)out_size; (void)ws_size;
  const float* h    = (const float*)d_in[0];
  const float* Wk   = (const float*)d_in[1];
  const float* Wq   = (const float*)d_in[2];
  const float* Wv   = (const float*)d_in[3];
  const float* Wa   = (const float*)d_in[4];
  const float* ratt = (const float*)d_in[5];
  const float* rmsg = (const float*)d_in[6];
  const float* pri  = (const float*)d_in[7];
  const float* skp  = (const float*)d_in[8];
  const int* ntype  = (const int*)d_in[9];
  const int* etyp   = (const int*)d_in[10];
  const int* rowi   = (const int*)d_in[11];
  const int* coli   = (const int*)d_in[12];
  float* out = (float*)d_out;

  char* p = (char*)d_ws;
  auto alloc = [&](size_t bytes) {
    void* q = (void*)p;
    p += (bytes + 255) & ~(size_t)255;
    return q;
  };
  unsigned short* hb    = (unsigned short*)alloc((size_t)NN * 256 * 2);
  unsigned short* Wt    = (unsigned short*)alloc((size_t)4 * 768 * 256 * 2);
  unsigned short* At    = (unsigned short*)alloc((size_t)4 * 256 * 256 * 2);
  unsigned short* relAT = (unsigned short*)alloc((size_t)NRL * NHH * 64 * 64 * 2);
  unsigned short* relMT = (unsigned short*)alloc((size_t)NRL * NHH * 64 * 64 * 2);
  float*          kf    = (float*)alloc((size_t)NN * 256 * 4);
  unsigned short* qb    = (unsigned short*)alloc((size_t)NN * 256 * 2);
  unsigned short* vb    = (unsigned short*)alloc((size_t)NN * 256 * 2);
  unsigned short* q_att = (unsigned short*)alloc((size_t)NRL * NN * 256 * 2);
  unsigned short* v_msg = (unsigned short*)alloc((size_t)NRL * NN * 256 * 2);
  float*          score = (float*)alloc((size_t)NE * 4 * 4);
  unsigned*       mmax  = (unsigned*)alloc((size_t)NN * 4 * 4);
  float*          denom = (float*)alloc((size_t)NN * 4 * 4);
  int* ncnt  = (int*)alloc(16);
  int* toff  = (int*)alloc(32);
  int* ncur  = (int*)alloc(16);
  int* nperm = (int*)alloc((size_t)NN * 4);
  int* ecnt  = (int*)alloc((size_t)NN * 4);
  int* eoff  = (int*)alloc((size_t)(NN + 1) * 4);
  int* ecur  = (int*)alloc((size_t)NN * 4);
  int* eperm = (int*)alloc((size_t)NE * 4);
  unsigned short* agg = (unsigned short*)alloc((size_t)NN * 256 * 2);

  // zero accumulators / counters (must re-zero every call)
  k_zero<<<(NN * 4 + 255) / 256, 256, 0, stream>>>(mmax, NN * 4);
  k_zero<<<(NN * 4 + 255) / 256, 256, 0, stream>>>((unsigned*)denom, NN * 4);
  k_zero<<<(NN + 255) / 256, 256, 0, stream>>>((unsigned*)ecnt, NN);
  k_zero<<<1, 256, 0, stream>>>((unsigned*)ncnt, 4);

  // casts / weight transposes
  k_cast<<<(NN * 256 + 255) / 256, 256, 0, stream>>>(h, hb, NN * 256);
  k_prep_wkqv<<<4 * 768, 256, 0, stream>>>(Wk, Wq, Wv, Wt);
  k_prep_a<<<4 * 256, 256, 0, stream>>>(Wa, At);
  k_prep_rel<<<(NRL * NHH * 64 * 64 + 255) / 256, 256, 0, stream>>>(ratt, rmsg, relAT, relMT);

  // node buckets by type
  k_count<<<(NN + 255) / 256, 256, 0, stream>>>(ntype, ncnt, NN);
  k_scan4<<<1, 1, 0, stream>>>(ncnt, toff, ncur);
  k_scatter<<<(NN + 255) / 256, 256, 0, stream>>>(ntype, ncur, nperm, NN);

  // CSR by destination
  k_count<<<(NE + 255) / 256, 256, 0, stream>>>(coli, ecnt, NE);
  k_scan_big<<<1, 1024, 0, stream>>>(ecnt, eoff, NN);
  k_copy<<<(NN + 255) / 256, 256, 0, stream>>>(eoff, ecur, NN);
  k_scatter<<<(NE + 255) / 256, 256, 0, stream>>>(coli, ecur, eperm, NE);

  // main pipeline
  k_gemm_kqv<<<dim3(15000, 4), 256, 0, stream>>>(hb, Wt, nperm, toff, kf, qb, vb);
  k_rel_gemm<<<dim3(40000, 2), 256, 0, stream>>>(qb, vb, relAT, relMT, q_att, v_msg);
  k_score<<<NE / 4, 256, 0, stream>>>(q_att, kf, etyp, rowi, coli, pri, score, mmax);
  k_exden<<<(NE * 4 + 255) / 256, 256, 0, stream>>>(coli, mmax, score, denom);
  k_agg<<<NN, 256, 0, stream>>>(eoff, eperm, etyp, rowi, score, denom, v_msg, agg);
  k_gemm_out<<<dim3(5000, 4), 256, 0, stream>>>(agg, At, nperm, toff, skp, out);
}

// Round 2
// 715.458 us; speedup vs baseline: 1.2281x; 1.2281x over previous
//
#include <hip/hip_runtime.h>

static constexpr int NN  = 20000;
static constexpr int NE  = 320000;
static constexpr int NTY = 4;
static constexpr int NRL = 8;
static constexpr int NB  = NRL * NN;   // 160000 bins = (rel, dst)

typedef short bf16x8 __attribute__((ext_vector_type(8)));
typedef float f32x4  __attribute__((ext_vector_type(4)));
typedef unsigned short u16x4 __attribute__((ext_vector_type(4)));

__device__ __forceinline__ unsigned short f2bf(float f) {
  unsigned u = __float_as_uint(f);
  u += 0x7fffu + ((u >> 16) & 1u);
  return (unsigned short)(u >> 16);
}
__device__ __forceinline__ float bf2f(unsigned short b) {
  return __uint_as_float(((unsigned)b) << 16);
}
__device__ __forceinline__ unsigned enc_f(float s) {
  unsigned u = __float_as_uint(s);
  return (u & 0x80000000u) ? ~u : (u | 0x80000000u);
}
__device__ __forceinline__ float dec_f(unsigned u) {
  return (u & 0x80000000u) ? __uint_as_float(u & 0x7fffffffu)
                           : __uint_as_float(~u);
}
__device__ __forceinline__ f32x4 mfma16(bf16x8 a, bf16x8 b, f32x4 c) {
  return __builtin_amdgcn_mfma_f32_16x16x32_bf16(a, b, c, 0, 0, 0);
}

// ---------------- init / prep ----------------
__global__ void k_init(unsigned* mmax, unsigned* denom, unsigned* bcnt, unsigned* ncnt) {
  int i = blockIdx.x * 256 + threadIdx.x;
  if (i < NN * 4)            mmax[i] = 0;
  else if (i < NN * 8)       denom[i - NN * 4] = 0;
  else if (i < NN * 8 + NB)  bcnt[i - NN * 8] = 0;
  else if (i < NN * 8 + NB + 4) ncnt[i - NN * 8 - NB] = 0;
}
__global__ void k_copy(const int* s, int* d, int n) {
  int i = blockIdx.x * 256 + threadIdx.x;
  if (i < n) d[i] = s[i];
}
__global__ void k_cast4(const float* in, unsigned short* out, int n4) {
  int i = blockIdx.x * 256 + threadIdx.x;
  if (i >= n4) return;
  const float* p = in + i * 4;
  u16x4 o;
  o[0] = f2bf(p[0]); o[1] = f2bf(p[1]); o[2] = f2bf(p[2]); o[3] = f2bf(p[3]);
  *(u16x4*)(out + i * 4) = o;
}
// Wt[t][j][i] = W{k|q|v}[t][i][j]  (B^T layout), j in [0,768)
__global__ void k_prep_wkqv(const float* Wk, const float* Wq, const float* Wv,
                            unsigned short* Wt) {
  int j = blockIdx.x % 768, t = blockIdx.x / 768, i = threadIdx.x;
  const float* src; int c;
  if (j < 256)      { src = Wk; c = j; }
  else if (j < 512) { src = Wq; c = j - 256; }
  else              { src = Wv; c = j - 512; }
  Wt[(t * 768 + j) * 256 + i] = f2bf(src[(t * 256 + i) * 256 + c]);
}
__global__ void k_prep_a(const float* Wa, unsigned short* At) {
  int j = blockIdx.x % 256, t = blockIdx.x / 256, i = threadIdx.x;
  At[(t * 256 + j) * 256 + i] = f2bf(Wa[(t * 256 + i) * 256 + j]);
}
// Ab = att cast (natural [rh][d][e]); Mt[rh][e][d] = msg[rh][d][e] (transposed)
__global__ void k_prep_rel2(const float* att, const float* msg,
                            unsigned short* Ab, unsigned short* Mt) {
  int idx = blockIdx.x * 256 + threadIdx.x;
  if (idx >= 32 * 4096) return;
  int rh = idx >> 12, x = (idx >> 6) & 63, y = idx & 63;
  Ab[idx] = f2bf(att[idx]);
  Mt[idx] = f2bf(msg[rh * 4096 + y * 64 + x]);
}

// ---------------- node buckets ----------------
__global__ void k_ncount(const int* key, int* cnt, int n) {
  int i = blockIdx.x * 256 + threadIdx.x;
  if (i < n) atomicAdd(&cnt[key[i]], 1);
}
__global__ void k_scan4(const int* cnt, int* off, int* cur) {
  if (threadIdx.x == 0 && blockIdx.x == 0) {
    int s = 0;
    for (int t = 0; t < NTY; ++t) { off[t] = s; cur[t] = s; s += cnt[t]; }
    off[NTY] = s;
  }
}
__global__ void k_nscatter(const int* key, int* cur, int* perm, int n) {
  int i = blockIdx.x * 256 + threadIdx.x;
  if (i < n) { int p = atomicAdd(&cur[key[i]], 1); perm[p] = i; }
}

// ---------------- edge CSR by (rel, dst) ----------------
__global__ void k_bcount(const int* etyp, const int* coli, int* cnt) {
  int e = blockIdx.x * 256 + threadIdx.x;
  if (e < NE) atomicAdd(&cnt[etyp[e] * NN + coli[e]], 1);
}
__global__ void k_scan1(const int* cnt, int* off, int* psum) {
  __shared__ int sm[256];
  int i = blockIdx.x * 256 + threadIdx.x;
  int v = cnt[i];
  sm[threadIdx.x] = v;
  __syncthreads();
  for (int d = 1; d < 256; d <<= 1) {
    int t = (threadIdx.x >= d) ? sm[threadIdx.x - d] : 0;
    __syncthreads();
    sm[threadIdx.x] += t;
    __syncthreads();
  }
  off[i] = sm[threadIdx.x] - v;
  if (threadIdx.x == 255) psum[blockIdx.x] = sm[255];
}
__global__ void k_scan2(int* psum) {
  __shared__ int sm[1024];
  int t = threadIdx.x;
  int v = (t < 625) ? psum[t] : 0;
  sm[t] = v;
  __syncthreads();
  for (int d = 1; d < 1024; d <<= 1) {
    int x = (t >= d) ? sm[t - d] : 0;
    __syncthreads();
    sm[t] += x;
    __syncthreads();
  }
  if (t < 625) psum[t] = sm[t] - v;
}
__global__ void k_scan3(int* off, const int* psum) {
  int i = blockIdx.x * 256 + threadIdx.x;
  off[i] += psum[blockIdx.x];
  if (i == 0) off[NB] = NE;
}
__global__ void k_escatter(const int* etyp, const int* rowi, const int* coli,
                           int* cur, int* je_src, int* je_dst) {
  int e = blockIdx.x * 256 + threadIdx.x;
  if (e >= NE) return;
  int bin = etyp[e] * NN + coli[e];
  int j = atomicAdd(&cur[bin], 1);
  je_src[j] = rowi[e];
  je_dst[j] = coli[e];
}

// ---------------- tile lists ----------------
__global__ void k_tiles(const int* toff, const int* boff, int* mt_t, int* mt_m,
                        int* t64r, int* t64j, int* gcnt) {
  __shared__ int ts[5], rs[9];
  if (threadIdx.x == 0) {
    int s = 0;
    for (int t = 0; t < NTY; ++t) { ts[t] = s; s += (toff[t + 1] - toff[t] + 15) >> 4; }
    ts[4] = s; gcnt[0] = s;
    s = 0;
    for (int r = 0; r < NRL; ++r) { rs[r] = s; s += (boff[(r + 1) * NN] - boff[r * NN] + 63) >> 6; }
    rs[8] = s; gcnt[1] = s;
  }
  __syncthreads();
  int nmt = ts[4], nt = rs[8];
  for (int i = threadIdx.x; i < nmt; i += 256) {
    int t = 0;
    while (t < 3 && i >= ts[t + 1]) ++t;
    mt_t[i] = t; mt_m[i] = i - ts[t];
  }
  for (int i = threadIdx.x; i < nt; i += 256) {
    int r = 0;
    while (r < 7 && i >= rs[r + 1]) ++r;
    t64r[i] = r; t64j[i] = boff[r * NN] + ((i - rs[r]) << 6);
  }
}

// ---------------- K1: typed K/Q/V projection ----------------
__global__ __launch_bounds__(256) void k_gemm_kqv(
    const unsigned short* __restrict__ hb, const unsigned short* __restrict__ Wt,
    const int* __restrict__ nperm, const int* __restrict__ toff,
    const int* __restrict__ mt_t, const int* __restrict__ mt_m,
    const int* __restrict__ gcnt,
    unsigned short* __restrict__ kb, unsigned short* __restrict__ qb,
    unsigned short* __restrict__ vb) {
  int mtile = blockIdx.x;
  if (mtile >= gcnt[0]) return;
  int wave = threadIdx.x >> 6, lane = threadIdx.x & 63;
  int t = mt_t[mtile], tm = mt_m[mtile];
  int tn = blockIdx.y * 4 + wave;
  int base = toff[t], cnt = toff[t + 1] - base;
  int lr = lane & 15, kq = lane >> 4;
  int arow = tm * 16 + lr;
  int node = nperm[base + (arow < cnt ? arow : cnt - 1)];
  const unsigned short* aptr = hb + node * 256 + kq * 8;
  const unsigned short* bptr = Wt + ((t * 768 + tn * 16 + lr) * 256) + kq * 8;
  f32x4 acc = {0.f, 0.f, 0.f, 0.f};
#pragma unroll
  for (int kk = 0; kk < 256; kk += 32)
    acc = mfma16(*(const bf16x8*)(aptr + kk), *(const bf16x8*)(bptr + kk), acc);
  int ccol = tn * 16 + lr;
#pragma unroll
  for (int i = 0; i < 4; ++i) {
    int crow = tm * 16 + kq * 4 + i;
    if (crow < cnt) {
      int nd = nperm[base + crow];
      unsigned short v = f2bf(acc[i]);
      if (ccol < 256)       kb[nd * 256 + ccol] = v;
      else if (ccol < 512)  qb[nd * 256 + (ccol - 256)] = v;
      else                  vb[nd * 256 + (ccol - 512)] = v;
    }
  }
}

// ---------------- K2: fused score (KT = K@A^T via MFMA, dot q, max) ----------------
__global__ __launch_bounds__(256) void k_score2(
    const unsigned short* __restrict__ kb, const unsigned short* __restrict__ qb,
    const unsigned short* __restrict__ Ab, const int* __restrict__ je_src,
    const int* __restrict__ je_dst, const int* __restrict__ boff,
    const float* __restrict__ pri, const int* __restrict__ t64r,
    const int* __restrict__ t64j, const int* __restrict__ gcnt,
    float* __restrict__ score, unsigned* __restrict__ mmax) {
  __shared__ unsigned short qs[4][16 * 264];
  int tile = blockIdx.x;
  if (tile >= gcnt[1]) return;
  int wave = threadIdx.x >> 6, lane = threadIdx.x & 63;
  int r = t64r[tile];
  int j0 = t64j[tile] + wave * 16;
  int jend = boff[(r + 1) * NN];
  if (j0 >= jend) return;
  int nv = jend - j0; if (nv > 16) nv = 16;
  unsigned short* q = qs[wave];
  for (int u = lane; u < 512; u += 64) {
    int row = u >> 5, seg = u & 31;
    int j = j0 + (row < nv ? row : nv - 1);
    int dst = je_dst[j];
    *(bf16x8*)(q + row * 264 + seg * 8) = *(const bf16x8*)(qb + dst * 256 + seg * 8);
  }
  int lr = lane & 15, kq = lane >> 4;
  int jm = j0 + (lr < nv ? lr : nv - 1);
  int src = je_src[jm];
  const unsigned short* ap = kb + src * 256 + kq * 8;
#pragma unroll
  for (int h = 0; h < 4; ++h) {
    bf16x8 a0 = *(const bf16x8*)(ap + h * 64);
    bf16x8 a1 = *(const bf16x8*)(ap + h * 64 + 32);
    const unsigned short* bp = Ab + (((r * 4 + h) * 64 + lr) * 64) + kq * 8;
    f32x4 sv = {0.f, 0.f, 0.f, 0.f};
#pragma unroll
    for (int tn = 0; tn < 4; ++tn) {
      f32x4 acc = {0.f, 0.f, 0.f, 0.f};
      acc = mfma16(a0, *(const bf16x8*)(bp + tn * 1024), acc);
      acc = mfma16(a1, *(const bf16x8*)(bp + tn * 1024 + 32), acc);
#pragma unroll
      for (int i = 0; i < 4; ++i) {
        float qv = bf2f(q[(kq * 4 + i) * 264 + h * 64 + tn * 16 + lr]);
        sv[i] += qv * acc[i];
      }
    }
#pragma unroll
    for (int m = 1; m <= 8; m <<= 1) {
      sv[0] += __shfl_xor(sv[0], m);
      sv[1] += __shfl_xor(sv[1], m);
      sv[2] += __shfl_xor(sv[2], m);
      sv[3] += __shfl_xor(sv[3], m);
    }
    if (lr == 0) {
      float pscale = pri[r * 4 + h] * 0.125f;
#pragma unroll
      for (int i = 0; i < 4; ++i) {
        int ei = kq * 4 + i;
        if (ei < nv) {
          int j = j0 + ei;
          float s = sv[i] * pscale;
          score[j * 4 + h] = s;
          atomicMax(&mmax[je_dst[j] * 4 + h], enc_f(s));
        }
      }
    }
  }
}

// ---------------- K3: exp + denom ----------------
__global__ void k_exden(const int* __restrict__ je_dst, const unsigned* __restrict__ mmax,
                        float* __restrict__ score, float* __restrict__ denom) {
  int idx = blockIdx.x * 256 + threadIdx.x;
  if (idx >= NE * 4) return;
  int j = idx >> 2, h = idx & 3;
  int dst = je_dst[j];
  float m = dec_f(mmax[dst * 4 + h]);
  float ex = __expf(score[idx] - m);
  score[idx] = ex;
  atomicAdd(&denom[dst * 4 + h], ex);
}

// ---------------- K4: weighted v segment-sum per (rel,dst) bin ----------------
__global__ __launch_bounds__(256) void k_wsum(
    const int* __restrict__ boff, const int* __restrict__ je_src,
    const float* __restrict__ ex, const float* __restrict__ denom,
    const unsigned short* __restrict__ vb, unsigned short* __restrict__ wsum) {
  int bin = blockIdx.x * 4 + (threadIdx.x >> 6);
  int lane = threadIdx.x & 63;
  int b0 = boff[bin], b1 = boff[bin + 1];
  if (b0 >= b1) return;
  int dst = bin % NN;
  float dinv = 1.f / denom[dst * 4 + (lane >> 4)];
  f32x4 acc = {0.f, 0.f, 0.f, 0.f};
  for (int j = b0; j < b1; ++j) {
    int src = je_src[j];
    float al = ex[j * 4 + (lane >> 4)];
    u16x4 v = *(const u16x4*)(vb + src * 256 + lane * 4);
    acc[0] += al * bf2f(v[0]); acc[1] += al * bf2f(v[1]);
    acc[2] += al * bf2f(v[2]); acc[3] += al * bf2f(v[3]);
  }
  u16x4 o;
  o[0] = f2bf(acc[0] * dinv); o[1] = f2bf(acc[1] * dinv);
  o[2] = f2bf(acc[2] * dinv); o[3] = f2bf(acc[3] * dinv);
  *(u16x4*)(wsum + (size_t)bin * 256 + lane * 4) = o;
}

// ---------------- K5: per-bin transform wsum @ M[r]  (in-place) ----------------
__global__ __launch_bounds__(256) void k_msg(
    const int* __restrict__ boff, const unsigned short* __restrict__ Mt,
    unsigned short* wsum) {
  int tile = blockIdx.x * 4 + (threadIdx.x >> 6);  // 10000 tiles of 16 bins
  int lane = threadIdx.x & 63;
  int r = tile / 1250;
  int lr = lane & 15, kq = lane >> 4;
  int bin = tile * 16 + lr;
  bool empty = (boff[bin] == boff[bin + 1]);
  const unsigned short* arow = wsum + (size_t)bin * 256;
  const bf16x8 z = {0, 0, 0, 0, 0, 0, 0, 0};
#pragma unroll
  for (int h = 0; h < 4; ++h) {
    bf16x8 a0 = *(const bf16x8*)(arow + h * 64 + kq * 8);
    bf16x8 a1 = *(const bf16x8*)(arow + h * 64 + 32 + kq * 8);
    if (empty) { a0 = z; a1 = z; }
    const unsigned short* bp = Mt + (((r * 4 + h) * 64 + lr) * 64) + kq * 8;
#pragma unroll
    for (int tn = 0; tn < 4; ++tn) {
      f32x4 acc = {0.f, 0.f, 0.f, 0.f};
      acc = mfma16(a0, *(const bf16x8*)(bp + tn * 1024), acc);
      acc = mfma16(a1, *(const bf16x8*)(bp + tn * 1024 + 32), acc);
#pragma unroll
      for (int i = 0; i < 4; ++i)
        wsum[(size_t)(tile * 16 + kq * 4 + i) * 256 + h * 64 + tn * 16 + lr] = f2bf(acc[i]);
    }
  }
}

// ---------------- K6: reduce 8 relations -> agg ----------------
__global__ void k_reduce(const unsigned short* __restrict__ wsum,
                         unsigned short* __restrict__ agg) {
  int idx = blockIdx.x * 256 + threadIdx.x;
  if (idx >= NN * 32) return;
  int dst = idx >> 5, c = idx & 31;
  float acc[8] = {0.f, 0.f, 0.f, 0.f, 0.f, 0.f, 0.f, 0.f};
#pragma unroll
  for (int r = 0; r < NRL; ++r) {
    bf16x8 v = *(const bf16x8*)(wsum + ((size_t)r * NN + dst) * 256 + c * 8);
#pragma unroll
    for (int k = 0; k < 8; ++k) acc[k] += bf2f((unsigned short)v[k]);
  }
  bf16x8 o;
#pragma unroll
  for (int k = 0; k < 8; ++k) o[k] = (short)f2bf(acc[k]);
  *(bf16x8*)(agg + dst * 256 + c * 8) = o;
}

// ---------------- K7: final typed projection + sigmoid(skip) ----------------
__global__ __launch_bounds__(256) void k_gemm_out(
    const unsigned short* __restrict__ agg, const unsigned short* __restrict__ At,
    const int* __restrict__ nperm, const int* __restrict__ toff,
    const int* __restrict__ mt_t, const int* __restrict__ mt_m,
    const int* __restrict__ gcnt,
    const float* __restrict__ skip, float* __restrict__ out) {
  int mtile = blockIdx.x;
  if (mtile >= gcnt[0]) return;
  int wave = threadIdx.x >> 6, lane = threadIdx.x & 63;
  int t = mt_t[mtile], tm = mt_m[mtile];
  int tn = blockIdx.y * 4 + wave;
  int base = toff[t], cnt = toff[t + 1] - base;
  int lr = lane & 15, kq = lane >> 4;
  int arow = tm * 16 + lr;
  int node = nperm[base + (arow < cnt ? arow : cnt - 1)];
  const unsigned short* aptr = agg + node * 256 + kq * 8;
  const unsigned short* bptr = At + (t * 256 + tn * 16 + lr) * 256 + kq * 8;
  f32x4 acc = {0.f, 0.f, 0.f, 0.f};
#pragma unroll
  for (int kk = 0; kk < 256; kk += 32)
    acc = mfma16(*(const bf16x8*)(aptr + kk), *(const bf16x8*)(bptr + kk), acc);
  float sg = 1.f / (1.f + __expf(-skip[t]));
  int ccol = tn * 16 + lr;
#pragma unroll
  for (int i = 0; i < 4; ++i) {
    int crow = tm * 16 + kq * 4 + i;
    if (crow < cnt) {
      int nd = nperm[base + crow];
      out[nd * 256 + ccol] = acc[i] * sg;
    }
  }
}

extern "C" void kernel_launch(void* const* d_in, const int* in_sizes, int n_in,
                              void* d_out, int out_size, void* d_ws, size_t ws_size,
                              hipStream_t stream) {
  (void)in_sizes; (void)n_in; (void)out_size; (void)ws_size;
  const float* h    = (const float*)d_in[0];
  const float* Wk   = (const float*)d_in[1];
  const float* Wq   = (const float*)d_in[2];
  const float* Wv   = (const float*)d_in[3];
  const float* Wa   = (const float*)d_in[4];
  const float* ratt = (const float*)d_in[5];
  const float* rmsg = (const float*)d_in[6];
  const float* pri  = (const float*)d_in[7];
  const float* skp  = (const float*)d_in[8];
  const int* ntype  = (const int*)d_in[9];
  const int* etyp   = (const int*)d_in[10];
  const int* rowi   = (const int*)d_in[11];
  const int* coli   = (const int*)d_in[12];
  float* out = (float*)d_out;

  char* p = (char*)d_ws;
  auto alloc = [&](size_t bytes) {
    void* q = (void*)p;
    p += (bytes + 255) & ~(size_t)255;
    return q;
  };
  unsigned short* hb  = (unsigned short*)alloc((size_t)NN * 256 * 2);
  unsigned short* Wt  = (unsigned short*)alloc((size_t)4 * 768 * 256 * 2);
  unsigned short* At  = (unsigned short*)alloc((size_t)4 * 256 * 256 * 2);
  unsigned short* Ab  = (unsigned short*)alloc((size_t)32 * 4096 * 2);
  unsigned short* Mt  = (unsigned short*)alloc((size_t)32 * 4096 * 2);
  unsigned short* kb  = (unsigned short*)alloc((size_t)NN * 256 * 2);
  unsigned short* qb  = (unsigned short*)alloc((size_t)NN * 256 * 2);
  unsigned short* vb  = (unsigned short*)alloc((size_t)NN * 256 * 2);
  float*    score = (float*)alloc((size_t)NE * 4 * 4);
  unsigned* mmax  = (unsigned*)alloc((size_t)NN * 4 * 4);
  float*    denom = (float*)alloc((size_t)NN * 4 * 4);
  int* ncnt  = (int*)alloc(16);
  int* toff  = (int*)alloc(32);
  int* ncur  = (int*)alloc(16);
  int* nperm = (int*)alloc((size_t)NN * 4);
  int* bcnt  = (int*)alloc((size_t)NB * 4);
  int* boff  = (int*)alloc((size_t)(NB + 1) * 4);
  int* bcur  = (int*)alloc((size_t)NB * 4);
  int* psum  = (int*)alloc((size_t)625 * 4);
  int* je_src = (int*)alloc((size_t)NE * 4);
  int* je_dst = (int*)alloc((size_t)NE * 4);
  unsigned short* wsum = (unsigned short*)alloc((size_t)NB * 256 * 2);
  unsigned short* agg  = (unsigned short*)alloc((size_t)NN * 256 * 2);
  int* mt_t = (int*)alloc((size_t)1253 * 4);
  int* mt_m = (int*)alloc((size_t)1253 * 4);
  int* t64r = (int*)alloc((size_t)5008 * 4);
  int* t64j = (int*)alloc((size_t)5008 * 4);
  int* gcnt = (int*)alloc(32);

  // init + prep
  k_init<<<(NN * 8 + NB + 4 + 255) / 256, 256, 0, stream>>>(mmax, (unsigned*)denom,
                                                            (unsigned*)bcnt, (unsigned*)ncnt);
  k_cast4<<<(NN * 64 + 255) / 256, 256, 0, stream>>>(h, hb, NN * 64);
  k_prep_wkqv<<<4 * 768, 256, 0, stream>>>(Wk, Wq, Wv, Wt);
  k_prep_a<<<4 * 256, 256, 0, stream>>>(Wa, At);
  k_prep_rel2<<<(32 * 4096 + 255) / 256, 256, 0, stream>>>(ratt, rmsg, Ab, Mt);

  // node buckets
  k_ncount<<<(NN + 255) / 256, 256, 0, stream>>>(ntype, ncnt, NN);
  k_scan4<<<1, 1, 0, stream>>>(ncnt, toff, ncur);
  k_nscatter<<<(NN + 255) / 256, 256, 0, stream>>>(ntype, ncur, nperm, NN);

  // edge CSR by (rel, dst)
  k_bcount<<<(NE + 255) / 256, 256, 0, stream>>>(etyp, coli, bcnt);
  k_scan1<<<625, 256, 0, stream>>>(bcnt, boff, psum);
  k_scan2<<<1, 1024, 0, stream>>>(psum);
  k_scan3<<<625, 256, 0, stream>>>(boff, psum);
  k_copy<<<625, 256, 0, stream>>>(boff, bcur, NB);
  k_escatter<<<(NE + 255) / 256, 256, 0, stream>>>(etyp, rowi, coli, bcur, je_src, je_dst);

  k_tiles<<<1, 256, 0, stream>>>(toff, boff, mt_t, mt_m, t64r, t64j, gcnt);

  // main pipeline
  k_gemm_kqv<<<dim3(1253, 12), 256, 0, stream>>>(hb, Wt, nperm, toff, mt_t, mt_m, gcnt,
                                                 kb, qb, vb);
  k_score2<<<5008, 256, 0, stream>>>(kb, qb, Ab, je_src, je_dst, boff, pri,
                                     t64r, t64j, gcnt, score, mmax);
  k_exden<<<(NE * 4 + 255) / 256, 256, 0, stream>>>(je_dst, mmax, score, denom);
  k_wsum<<<NB / 4, 256, 0, stream>>>(boff, je_src, score, denom, vb, wsum);
  k_msg<<<2500, 256, 0, stream>>>(boff, Mt, wsum);
  k_reduce<<<(NN * 32 + 255) / 256, 256, 0, stream>>>(wsum, agg);
  k_gemm_out<<<dim3(1253, 4), 256, 0, stream>>>(agg, At, nperm, toff, mt_t, mt_m, gcnt,
                                                skp, out);
}

// Round 3
// 696.777 us; speedup vs baseline: 1.2611x; 1.0268x over previous
//
#include <hip/hip_runtime.h>

static constexpr int NN  = 20000;
static constexpr int NE  = 320000;
static constexpr int NTY = 4;
static constexpr int NRL = 8;
static constexpr int NB  = NRL * NN;   // 160000 bins = (rel, dst)
static constexpr int MAXT16 = NE / 16 + NRL;  // 20008 max 16-edge groups

typedef short bf16x8 __attribute__((ext_vector_type(8)));
typedef float f32x4  __attribute__((ext_vector_type(4)));
typedef unsigned short u16x4 __attribute__((ext_vector_type(4)));

__device__ __forceinline__ unsigned short f2bf(float f) {
  unsigned u = __float_as_uint(f);
  u += 0x7fffu + ((u >> 16) & 1u);
  return (unsigned short)(u >> 16);
}
__device__ __forceinline__ float bf2f(unsigned short b) {
  return __uint_as_float(((unsigned)b) << 16);
}
__device__ __forceinline__ unsigned enc_f(float s) {
  unsigned u = __float_as_uint(s);
  return (u & 0x80000000u) ? ~u : (u | 0x80000000u);
}
__device__ __forceinline__ float dec_f(unsigned u) {
  return (u & 0x80000000u) ? __uint_as_float(u & 0x7fffffffu)
                           : __uint_as_float(~u);
}
__device__ __forceinline__ f32x4 mfma16(bf16x8 a, bf16x8 b, f32x4 c) {
  return __builtin_amdgcn_mfma_f32_16x16x32_bf16(a, b, c, 0, 0, 0);
}

// ---------------- init / prep ----------------
__global__ void k_init(unsigned* mmax, unsigned* denom, unsigned* bcnt, unsigned* ncnt) {
  int i = blockIdx.x * 256 + threadIdx.x;
  if (i < NN * 4)            mmax[i] = 0;
  else if (i < NN * 8)       denom[i - NN * 4] = 0;
  else if (i < NN * 8 + NB)  bcnt[i - NN * 8] = 0;
  else if (i < NN * 8 + NB + 4) ncnt[i - NN * 8 - NB] = 0;
}
__global__ void k_copy(const int* s, int* d, int n) {
  int i = blockIdx.x * 256 + threadIdx.x;
  if (i < n) d[i] = s[i];
}
__global__ void k_cast4(const float* in, unsigned short* out, int n4) {
  int i = blockIdx.x * 256 + threadIdx.x;
  if (i >= n4) return;
  const float* p = in + i * 4;
  u16x4 o;
  o[0] = f2bf(p[0]); o[1] = f2bf(p[1]); o[2] = f2bf(p[2]); o[3] = f2bf(p[3]);
  *(u16x4*)(out + i * 4) = o;
}
// Wt[t][j][i] = W{k|q|v}[t][i][j]  (B^T layout), j in [0,768)
__global__ void k_prep_wkqv(const float* Wk, const float* Wq, const float* Wv,
                            unsigned short* Wt) {
  int j = blockIdx.x % 768, t = blockIdx.x / 768, i = threadIdx.x;
  const float* src; int c;
  if (j < 256)      { src = Wk; c = j; }
  else if (j < 512) { src = Wq; c = j - 256; }
  else              { src = Wv; c = j - 512; }
  Wt[(t * 768 + j) * 256 + i] = f2bf(src[(t * 256 + i) * 256 + c]);
}
__global__ void k_prep_a(const float* Wa, unsigned short* At) {
  int j = blockIdx.x % 256, t = blockIdx.x / 256, i = threadIdx.x;
  At[(t * 256 + j) * 256 + i] = f2bf(Wa[(t * 256 + i) * 256 + j]);
}
// Ab = att cast (natural [rh][d][e]); Mt[rh][e][d] = msg[rh][d][e] (transposed)
__global__ void k_prep_rel2(const float* att, const float* msg,
                            unsigned short* Ab, unsigned short* Mt) {
  int idx = blockIdx.x * 256 + threadIdx.x;
  if (idx >= 32 * 4096) return;
  int rh = idx >> 12, x = (idx >> 6) & 63, y = idx & 63;
  Ab[idx] = f2bf(att[idx]);
  Mt[idx] = f2bf(msg[rh * 4096 + y * 64 + x]);
}

// ---------------- node buckets ----------------
__global__ void k_ncount(const int* key, int* cnt, int n) {
  int i = blockIdx.x * 256 + threadIdx.x;
  if (i < n) atomicAdd(&cnt[key[i]], 1);
}
__global__ void k_scan4(const int* cnt, int* off, int* cur) {
  if (threadIdx.x == 0 && blockIdx.x == 0) {
    int s = 0;
    for (int t = 0; t < NTY; ++t) { off[t] = s; cur[t] = s; s += cnt[t]; }
    off[NTY] = s;
  }
}
__global__ void k_nscatter(const int* key, int* cur, int* perm, int n) {
  int i = blockIdx.x * 256 + threadIdx.x;
  if (i < n) { int p = atomicAdd(&cur[key[i]], 1); perm[p] = i; }
}

// ---------------- edge CSR by (rel, dst) ----------------
__global__ void k_bcount(const int* etyp, const int* coli, int* cnt) {
  int e = blockIdx.x * 256 + threadIdx.x;
  if (e < NE) atomicAdd(&cnt[etyp[e] * NN + coli[e]], 1);
}
__global__ void k_scan1(const int* cnt, int* off, int* psum) {
  __shared__ int sm[256];
  int i = blockIdx.x * 256 + threadIdx.x;
  int v = cnt[i];
  sm[threadIdx.x] = v;
  __syncthreads();
  for (int d = 1; d < 256; d <<= 1) {
    int t = (threadIdx.x >= d) ? sm[threadIdx.x - d] : 0;
    __syncthreads();
    sm[threadIdx.x] += t;
    __syncthreads();
  }
  off[i] = sm[threadIdx.x] - v;
  if (threadIdx.x == 255) psum[blockIdx.x] = sm[255];
}
__global__ void k_scan2(int* psum) {
  __shared__ int sm[1024];
  int t = threadIdx.x;
  int v = (t < 625) ? psum[t] : 0;
  sm[t] = v;
  __syncthreads();
  for (int d = 1; d < 1024; d <<= 1) {
    int x = (t >= d) ? sm[t - d] : 0;
    __syncthreads();
    sm[t] += x;
    __syncthreads();
  }
  if (t < 625) psum[t] = sm[t] - v;
}
__global__ void k_scan3(int* off, const int* psum) {
  int i = blockIdx.x * 256 + threadIdx.x;
  off[i] += psum[blockIdx.x];
  if (i == 0) off[NB] = NE;
}
__global__ void k_escatter(const int* etyp, const int* rowi, const int* coli,
                           int* cur, int* je_src, int* je_dst) {
  int e = blockIdx.x * 256 + threadIdx.x;
  if (e >= NE) return;
  int bin = etyp[e] * NN + coli[e];
  int j = atomicAdd(&cur[bin], 1);
  je_src[j] = rowi[e];
  je_dst[j] = coli[e];
}

// ---------------- tile lists ----------------
__global__ void k_tiles(const int* toff, const int* boff, int* mt_t, int* mt_m,
                        int* t16r, int* t16j, int* gcnt) {
  __shared__ int ts[5], rs[9];
  if (threadIdx.x == 0) {
    int s = 0;
    for (int t = 0; t < NTY; ++t) { ts[t] = s; s += (toff[t + 1] - toff[t] + 15) >> 4; }
    ts[4] = s; gcnt[0] = s;
    s = 0;
    for (int r = 0; r < NRL; ++r) { rs[r] = s; s += (boff[(r + 1) * NN] - boff[r * NN] + 15) >> 4; }
    rs[8] = s; gcnt[1] = s;
  }
  __syncthreads();
  int nmt = ts[4], nt = rs[8];
  for (int i = threadIdx.x; i < nmt; i += 256) {
    int t = 0;
    while (t < 3 && i >= ts[t + 1]) ++t;
    mt_t[i] = t; mt_m[i] = i - ts[t];
  }
  for (int i = threadIdx.x; i < nt; i += 256) {
    int r = 0;
    while (r < 7 && i >= rs[r + 1]) ++r;
    t16r[i] = r; t16j[i] = boff[r * NN] + ((i - rs[r]) << 4);
  }
}

// ---------------- K1: typed K/Q/V projection ----------------
__global__ __launch_bounds__(256) void k_gemm_kqv(
    const unsigned short* __restrict__ hb, const unsigned short* __restrict__ Wt,
    const int* __restrict__ nperm, const int* __restrict__ toff,
    const int* __restrict__ mt_t, const int* __restrict__ mt_m,
    const int* __restrict__ gcnt,
    unsigned short* __restrict__ kb, unsigned short* __restrict__ qb,
    unsigned short* __restrict__ vb) {
  int mtile = blockIdx.x;
  if (mtile >= gcnt[0]) return;
  int wave = threadIdx.x >> 6, lane = threadIdx.x & 63;
  int t = mt_t[mtile], tm = mt_m[mtile];
  int tn = blockIdx.y * 4 + wave;
  int base = toff[t], cnt = toff[t + 1] - base;
  int lr = lane & 15, kq = lane >> 4;
  int arow = tm * 16 + lr;
  int node = nperm[base + (arow < cnt ? arow : cnt - 1)];
  const unsigned short* aptr = hb + node * 256 + kq * 8;
  const unsigned short* bptr = Wt + ((t * 768 + tn * 16 + lr) * 256) + kq * 8;
  f32x4 acc = {0.f, 0.f, 0.f, 0.f};
#pragma unroll
  for (int kk = 0; kk < 256; kk += 32)
    acc = mfma16(*(const bf16x8*)(aptr + kk), *(const bf16x8*)(bptr + kk), acc);
  int ccol = tn * 16 + lr;
#pragma unroll
  for (int i = 0; i < 4; ++i) {
    int crow = tm * 16 + kq * 4 + i;
    if (crow < cnt) {
      int nd = nperm[base + crow];
      unsigned short v = f2bf(acc[i]);
      if (ccol < 256)       kb[nd * 256 + ccol] = v;
      else if (ccol < 512)  qb[nd * 256 + (ccol - 256)] = v;
      else                  vb[nd * 256 + (ccol - 512)] = v;
    }
  }
}

// ---------------- K2: fused score, LDS-free ----------------
// Z[d, edge] = sum_e A_r[d,e] * k[src_edge, e]  (MFMA, edges on columns)
// score[edge,h] = sum_d q[dst_edge, d] * Z[d, edge]  (per-own-lane 8B q loads)
__global__ __launch_bounds__(256) void k_score2(
    const unsigned short* __restrict__ kb, const unsigned short* __restrict__ qb,
    const unsigned short* __restrict__ Ab, const int* __restrict__ je_src,
    const int* __restrict__ je_dst, const int* __restrict__ boff,
    const float* __restrict__ pri, const int* __restrict__ t16r,
    const int* __restrict__ t16j, const int* __restrict__ gcnt,
    float* __restrict__ score, unsigned* __restrict__ mmax) {
  int tile = blockIdx.x * 4 + (threadIdx.x >> 6);
  if (tile >= gcnt[1]) return;
  int lane = threadIdx.x & 63;
  int lr = lane & 15, kq = lane >> 4;
  int r = t16r[tile];
  int j0 = t16j[tile];
  int nv = boff[(r + 1) * NN] - j0; if (nv > 16) nv = 16;
  int j = j0 + (lr < nv ? lr : nv - 1);
  int src = je_src[j], dst = je_dst[j];
  const unsigned short* kp = kb + src * 256 + kq * 8;
  const unsigned short* qp = qb + dst * 256 + kq * 4;
  float sv[4];
#pragma unroll
  for (int h = 0; h < 4; ++h) {
    bf16x8 b0 = *(const bf16x8*)(kp + h * 64);
    bf16x8 b1 = *(const bf16x8*)(kp + h * 64 + 32);
    const unsigned short* arow = Ab + (((r * 4 + h) * 64 + lr) * 64) + kq * 8;
    float s = 0.f;
#pragma unroll
    for (int mt = 0; mt < 4; ++mt) {
      f32x4 acc = {0.f, 0.f, 0.f, 0.f};
      acc = mfma16(*(const bf16x8*)(arow + mt * 1024), b0, acc);
      acc = mfma16(*(const bf16x8*)(arow + mt * 1024 + 32), b1, acc);
      u16x4 qv = *(const u16x4*)(qp + h * 64 + mt * 16);
      s += bf2f(qv[0]) * acc[0] + bf2f(qv[1]) * acc[1] +
           bf2f(qv[2]) * acc[2] + bf2f(qv[3]) * acc[3];
    }
    s += __shfl_xor(s, 16);
    s += __shfl_xor(s, 32);
    sv[h] = s * pri[r * 4 + h] * 0.125f;
  }
  if (lr < nv) {
    if (kq == 0) {
      f32x4 o = {sv[0], sv[1], sv[2], sv[3]};
      *(f32x4*)(score + (size_t)(j0 + lr) * 4) = o;
    }
    float m = (kq == 0) ? sv[0] : (kq == 1) ? sv[1] : (kq == 2) ? sv[2] : sv[3];
    atomicMax(&mmax[dst * 4 + kq], enc_f(m));
  }
}

// ---------------- K3: weighted v segment-sum per (rel,dst) bin (ex inline) ----------------
__global__ __launch_bounds__(256) void k_wsum(
    const int* __restrict__ boff, const int* __restrict__ je_src,
    const float* __restrict__ score, const unsigned* __restrict__ mmax,
    const unsigned short* __restrict__ vb, float* __restrict__ denom,
    unsigned short* __restrict__ wsum) {
  int bin = blockIdx.x * 4 + (threadIdx.x >> 6);
  int lane = threadIdx.x & 63;
  int b0 = boff[bin], b1 = boff[bin + 1];
  if (b0 >= b1) return;
  int dst = bin % NN;
  int h = lane >> 4;
  float m = dec_f(mmax[dst * 4 + h]);
  f32x4 acc = {0.f, 0.f, 0.f, 0.f};
  float esum = 0.f;
  for (int j = b0; j < b1; ++j) {
    int src = je_src[j];
    float ex = __expf(score[j * 4 + h] - m);
    esum += ex;
    u16x4 v = *(const u16x4*)(vb + src * 256 + lane * 4);
    acc[0] += ex * bf2f(v[0]); acc[1] += ex * bf2f(v[1]);
    acc[2] += ex * bf2f(v[2]); acc[3] += ex * bf2f(v[3]);
  }
  u16x4 o;
  o[0] = f2bf(acc[0]); o[1] = f2bf(acc[1]);
  o[2] = f2bf(acc[2]); o[3] = f2bf(acc[3]);
  *(u16x4*)(wsum + (size_t)bin * 256 + lane * 4) = o;
  if ((lane & 15) == 0) atomicAdd(&denom[dst * 4 + h], esum);
}

// ---------------- K4: fused msg-transform + relation-reduce + normalize ----------------
// agg[dst, h*64+e'] = (sum_r  wsum[r,dst, h*64+:] @ M_r[h])  / denom[dst,h]
__global__ __launch_bounds__(256) void k_msgred(
    const int* __restrict__ boff, const unsigned short* __restrict__ Mt,
    const unsigned short* __restrict__ wsum, const float* __restrict__ denom,
    unsigned short* __restrict__ agg) {
  int tile = blockIdx.x;            // 1250 dst-tiles of 16
  int h = threadIdx.x >> 6;         // wave = head
  int lane = threadIdx.x & 63;
  int lr = lane & 15, kq = lane >> 4;
  int dstA = tile * 16 + lr;        // a-frag row
  const bf16x8 z = {0, 0, 0, 0, 0, 0, 0, 0};
  f32x4 acc[4] = {{0.f,0.f,0.f,0.f},{0.f,0.f,0.f,0.f},{0.f,0.f,0.f,0.f},{0.f,0.f,0.f,0.f}};
#pragma unroll
  for (int r = 0; r < NRL; ++r) {
    int bin = r * NN + dstA;
    bool empty = (boff[bin] == boff[bin + 1]);
    const unsigned short* ap = wsum + (size_t)bin * 256 + h * 64 + kq * 8;
    bf16x8 a0 = empty ? z : *(const bf16x8*)ap;
    bf16x8 a1 = empty ? z : *(const bf16x8*)(ap + 32);
    const unsigned short* bp = Mt + (((r * 4 + h) * 64 + lr) * 64) + kq * 8;
#pragma unroll
    for (int tn = 0; tn < 4; ++tn) {
      acc[tn] = mfma16(a0, *(const bf16x8*)(bp + tn * 1024), acc[tn]);
      acc[tn] = mfma16(a1, *(const bf16x8*)(bp + tn * 1024 + 32), acc[tn]);
    }
  }
  float dinv[4];
#pragma unroll
  for (int i = 0; i < 4; ++i) {
    float d = denom[(tile * 16 + kq * 4 + i) * 4 + h];
    dinv[i] = d > 0.f ? 1.f / d : 0.f;
  }
#pragma unroll
  for (int tn = 0; tn < 4; ++tn)
#pragma unroll
    for (int i = 0; i < 4; ++i)
      agg[(size_t)(tile * 16 + kq * 4 + i) * 256 + h * 64 + tn * 16 + lr] =
          f2bf(acc[tn][i] * dinv[i]);
}

// ---------------- K5: final typed projection + sigmoid(skip) ----------------
__global__ __launch_bounds__(256) void k_gemm_out(
    const unsigned short* __restrict__ agg, const unsigned short* __restrict__ At,
    const int* __restrict__ nperm, const int* __restrict__ toff,
    const int* __restrict__ mt_t, const int* __restrict__ mt_m,
    const int* __restrict__ gcnt,
    const float* __restrict__ skip, float* __restrict__ out) {
  int mtile = blockIdx.x;
  if (mtile >= gcnt[0]) return;
  int wave = threadIdx.x >> 6, lane = threadIdx.x & 63;
  int t = mt_t[mtile], tm = mt_m[mtile];
  int tn = blockIdx.y * 4 + wave;
  int base = toff[t], cnt = toff[t + 1] - base;
  int lr = lane & 15, kq = lane >> 4;
  int arow = tm * 16 + lr;
  int node = nperm[base + (arow < cnt ? arow : cnt - 1)];
  const unsigned short* aptr = agg + node * 256 + kq * 8;
  const unsigned short* bptr = At + (t * 256 + tn * 16 + lr) * 256 + kq * 8;
  f32x4 acc = {0.f, 0.f, 0.f, 0.f};
#pragma unroll
  for (int kk = 0; kk < 256; kk += 32)
    acc = mfma16(*(const bf16x8*)(aptr + kk), *(const bf16x8*)(bptr + kk), acc);
  float sg = 1.f / (1.f + __expf(-skip[t]));
  int ccol = tn * 16 + lr;
#pragma unroll
  for (int i = 0; i < 4; ++i) {
    int crow = tm * 16 + kq * 4 + i;
    if (crow < cnt) {
      int nd = nperm[base + crow];
      out[nd * 256 + ccol] = acc[i] * sg;
    }
  }
}

extern "C" void kernel_launch(void* const* d_in, const int* in_sizes, int n_in,
                              void* d_out, int out_size, void* d_ws, size_t ws_size,
                              hipStream_t stream) {
  (void)in_sizes; (void)n_in; (void)out_size; (void)ws_size;
  const float* h    = (const float*)d_in[0];
  const float* Wk   = (const float*)d_in[1];
  const float* Wq   = (const float*)d_in[2];
  const float* Wv   = (const float*)d_in[3];
  const float* Wa   = (const float*)d_in[4];
  const float* ratt = (const float*)d_in[5];
  const float* rmsg = (const float*)d_in[6];
  const float* pri  = (const float*)d_in[7];
  const float* skp  = (const float*)d_in[8];
  const int* ntype  = (const int*)d_in[9];
  const int* etyp   = (const int*)d_in[10];
  const int* rowi   = (const int*)d_in[11];
  const int* coli   = (const int*)d_in[12];
  float* out = (float*)d_out;

  char* p = (char*)d_ws;
  auto alloc = [&](size_t bytes) {
    void* q = (void*)p;
    p += (bytes + 255) & ~(size_t)255;
    return q;
  };
  unsigned short* hb  = (unsigned short*)alloc((size_t)NN * 256 * 2);
  unsigned short* Wt  = (unsigned short*)alloc((size_t)4 * 768 * 256 * 2);
  unsigned short* At  = (unsigned short*)alloc((size_t)4 * 256 * 256 * 2);
  unsigned short* Ab  = (unsigned short*)alloc((size_t)32 * 4096 * 2);
  unsigned short* Mt  = (unsigned short*)alloc((size_t)32 * 4096 * 2);
  unsigned short* kb  = (unsigned short*)alloc((size_t)NN * 256 * 2);
  unsigned short* qb  = (unsigned short*)alloc((size_t)NN * 256 * 2);
  unsigned short* vb  = (unsigned short*)alloc((size_t)NN * 256 * 2);
  float*    score = (float*)alloc((size_t)NE * 4 * 4);
  unsigned* mmax  = (unsigned*)alloc((size_t)NN * 4 * 4);
  float*    denom = (float*)alloc((size_t)NN * 4 * 4);
  int* ncnt  = (int*)alloc(16);
  int* toff  = (int*)alloc(32);
  int* ncur  = (int*)alloc(16);
  int* nperm = (int*)alloc((size_t)NN * 4);
  int* bcnt  = (int*)alloc((size_t)NB * 4);
  int* boff  = (int*)alloc((size_t)(NB + 1) * 4);
  int* bcur  = (int*)alloc((size_t)NB * 4);
  int* psum  = (int*)alloc((size_t)625 * 4);
  int* je_src = (int*)alloc((size_t)NE * 4);
  int* je_dst = (int*)alloc((size_t)NE * 4);
  unsigned short* wsum = (unsigned short*)alloc((size_t)NB * 256 * 2);
  unsigned short* agg  = (unsigned short*)alloc((size_t)NN * 256 * 2);
  int* mt_t = (int*)alloc((size_t)1253 * 4);
  int* mt_m = (int*)alloc((size_t)1253 * 4);
  int* t16r = (int*)alloc((size_t)(MAXT16 + 32) * 4);
  int* t16j = (int*)alloc((size_t)(MAXT16 + 32) * 4);
  int* gcnt = (int*)alloc(32);

  // init + prep
  k_init<<<(NN * 8 + NB + 4 + 255) / 256, 256, 0, stream>>>(mmax, (unsigned*)denom,
                                                            (unsigned*)bcnt, (unsigned*)ncnt);
  k_cast4<<<(NN * 64 + 255) / 256, 256, 0, stream>>>(h, hb, NN * 64);
  k_prep_wkqv<<<4 * 768, 256, 0, stream>>>(Wk, Wq, Wv, Wt);
  k_prep_a<<<4 * 256, 256, 0, stream>>>(Wa, At);
  k_prep_rel2<<<(32 * 4096 + 255) / 256, 256, 0, stream>>>(ratt, rmsg, Ab, Mt);

  // node buckets
  k_ncount<<<(NN + 255) / 256, 256, 0, stream>>>(ntype, ncnt, NN);
  k_scan4<<<1, 1, 0, stream>>>(ncnt, toff, ncur);
  k_nscatter<<<(NN + 255) / 256, 256, 0, stream>>>(ntype, ncur, nperm, NN);

  // edge CSR by (rel, dst)
  k_bcount<<<(NE + 255) / 256, 256, 0, stream>>>(etyp, coli, bcnt);
  k_scan1<<<625, 256, 0, stream>>>(bcnt, boff, psum);
  k_scan2<<<1, 1024, 0, stream>>>(psum);
  k_scan3<<<625, 256, 0, stream>>>(boff, psum);
  k_copy<<<625, 256, 0, stream>>>(boff, bcur, NB);
  k_escatter<<<(NE + 255) / 256, 256, 0, stream>>>(etyp, rowi, coli, bcur, je_src, je_dst);

  k_tiles<<<1, 256, 0, stream>>>(toff, boff, mt_t, mt_m, t16r, t16j, gcnt);

  // main pipeline
  k_gemm_kqv<<<dim3(1253, 12), 256, 0, stream>>>(hb, Wt, nperm, toff, mt_t, mt_m, gcnt,
                                                 kb, qb, vb);
  k_score2<<<(MAXT16 + 3) / 4, 256, 0, stream>>>(kb, qb, Ab, je_src, je_dst, boff, pri,
                                                 t16r, t16j, gcnt, score, mmax);
  k_wsum<<<NB / 4, 256, 0, stream>>>(boff, je_src, score, mmax, vb, denom, wsum);
  k_msgred<<<1250, 256, 0, stream>>>(boff, Mt, wsum, denom, agg);
  k_gemm_out<<<dim3(1253, 4), 256, 0, stream>>>(agg, At, nperm, toff, mt_t, mt_m, gcnt,
                                                skp, out);
}

// Round 4
// 554.659 us; speedup vs baseline: 1.5842x; 1.2562x over previous
//
#include <hip/hip_runtime.h>

static constexpr int NN  = 20000;
static constexpr int NE  = 320000;
static constexpr int NTY = 4;
static constexpr int NRL = 8;
static constexpr int NB  = NRL * NN;   // 160000 bins = (rel, dst)

typedef short bf16x8 __attribute__((ext_vector_type(8)));
typedef float f32x4  __attribute__((ext_vector_type(4)));
typedef unsigned short u16x4 __attribute__((ext_vector_type(4)));

__device__ __forceinline__ unsigned short f2bf(float f) {
  unsigned u = __float_as_uint(f);
  u += 0x7fffu + ((u >> 16) & 1u);
  return (unsigned short)(u >> 16);
}
__device__ __forceinline__ float bf2f(unsigned short b) {
  return __uint_as_float(((unsigned)b) << 16);
}
__device__ __forceinline__ f32x4 mfma16(bf16x8 a, bf16x8 b, f32x4 c) {
  return __builtin_amdgcn_mfma_f32_16x16x32_bf16(a, b, c, 0, 0, 0);
}

// ---------------- init / prep ----------------
__global__ void k_init(int* bcnt, int* ncnt) {
  int i = blockIdx.x * 256 + threadIdx.x;
  if (i < NB) bcnt[i] = 0;
  if (i < NTY) ncnt[i] = 0;
}
__global__ void k_cast4(const float* in, unsigned short* out, int n4) {
  int i = blockIdx.x * 256 + threadIdx.x;
  if (i >= n4) return;
  const float* p = in + i * 4;
  u16x4 o;
  o[0] = f2bf(p[0]); o[1] = f2bf(p[1]); o[2] = f2bf(p[2]); o[3] = f2bf(p[3]);
  *(u16x4*)(out + i * 4) = o;
}
// Wt[t][j][i] = W{k|q|v}[t][i][j]  (B^T layout), j in [0,768)
__global__ void k_prep_wkqv(const float* Wk, const float* Wq, const float* Wv,
                            unsigned short* Wt) {
  int j = blockIdx.x % 768, t = blockIdx.x / 768, i = threadIdx.x;
  const float* src; int c;
  if (j < 256)      { src = Wk; c = j; }
  else if (j < 512) { src = Wq; c = j - 256; }
  else              { src = Wv; c = j - 512; }
  Wt[(t * 768 + j) * 256 + i] = f2bf(src[(t * 256 + i) * 256 + c]);
}
__global__ void k_prep_a(const float* Wa, unsigned short* At) {
  int j = blockIdx.x % 256, t = blockIdx.x / 256, i = threadIdx.x;
  At[(t * 256 + j) * 256 + i] = f2bf(Wa[(t * 256 + i) * 256 + j]);
}
// Att[rh][e][d] = att[rh][d][e];  Mt[rh][e][d] = msg[rh][d][e]
__global__ void k_prep_rel2(const float* att, const float* msg,
                            unsigned short* Att, unsigned short* Mt) {
  int idx = blockIdx.x * 256 + threadIdx.x;
  if (idx >= 32 * 4096) return;
  int rh = idx >> 12, e = (idx >> 6) & 63, d = idx & 63;
  Att[idx] = f2bf(att[rh * 4096 + d * 64 + e]);
  Mt[idx]  = f2bf(msg[rh * 4096 + d * 64 + e]);
}

// ---------------- counts ----------------
__global__ void k_count_all(const int* ntype, const int* etyp, const int* coli,
                            int* ncnt, int* bcnt) {
  int i = blockIdx.x * 256 + threadIdx.x;
  if (i < NE) atomicAdd(&bcnt[etyp[i] * NN + coli[i]], 1);
  if (i < NN) atomicAdd(&ncnt[ntype[i]], 1);
}
// node-type scan + row-tile list
__global__ void k_meta(const int* ncnt, int* toff, int* ncur,
                       int* mt_t, int* mt_m, int* gcnt) {
  __shared__ int ts[5];
  if (threadIdx.x == 0) {
    int s = 0;
    for (int t = 0; t < NTY; ++t) { toff[t] = s; ncur[t] = s; s += ncnt[t]; }
    toff[NTY] = s;
    s = 0;
    for (int t = 0; t < NTY; ++t) { ts[t] = s; s += (ncnt[t] + 15) >> 4; }
    ts[4] = s; gcnt[0] = s;
  }
  __syncthreads();
  int nmt = ts[4];
  for (int i = threadIdx.x; i < nmt; i += 256) {
    int t = 0;
    while (t < 3 && i >= ts[t + 1]) ++t;
    mt_t[i] = t; mt_m[i] = i - ts[t];
  }
}
__global__ void k_nscatter(const int* key, int* cur, int* perm, int n) {
  int i = blockIdx.x * 256 + threadIdx.x;
  if (i < n) { int p = atomicAdd(&cur[key[i]], 1); perm[p] = i; }
}

// ---------------- bin scans ----------------
__global__ void k_scan1(const int* cnt, int* off, int* psum) {
  __shared__ int sm[256];
  int i = blockIdx.x * 256 + threadIdx.x;
  int v = cnt[i];
  sm[threadIdx.x] = v;
  __syncthreads();
  for (int d = 1; d < 256; d <<= 1) {
    int t = (threadIdx.x >= d) ? sm[threadIdx.x - d] : 0;
    __syncthreads();
    sm[threadIdx.x] += t;
    __syncthreads();
  }
  off[i] = sm[threadIdx.x] - v;
  if (threadIdx.x == 255) psum[blockIdx.x] = sm[255];
}
__global__ void k_scan2(int* psum) {
  __shared__ int sm[1024];
  int t = threadIdx.x;
  int v = (t < 625) ? psum[t] : 0;
  sm[t] = v;
  __syncthreads();
  for (int d = 1; d < 1024; d <<= 1) {
    int x = (t >= d) ? sm[t - d] : 0;
    __syncthreads();
    sm[t] += x;
    __syncthreads();
  }
  if (t < 625) psum[t] = sm[t] - v;
}
__global__ void k_scan3(int* off, int* cur, const int* psum) {
  int i = blockIdx.x * 256 + threadIdx.x;
  int v = off[i] + psum[blockIdx.x];
  off[i] = v; cur[i] = v;
  if (i == 0) off[NB] = NE;
}
__global__ void k_escatter(const int* etyp, const int* rowi, const int* coli,
                           int* cur, int* je_src) {
  int e = blockIdx.x * 256 + threadIdx.x;
  if (e >= NE) return;
  int bin = etyp[e] * NN + coli[e];
  int j = atomicAdd(&cur[bin], 1);
  je_src[j] = rowi[e];
}

// ---------------- K1: typed K/Q/V projection (A-frags in registers, 48 col-tiles/block) ----
__global__ __launch_bounds__(256) void k_gemm_kqv(
    const unsigned short* __restrict__ hb, const unsigned short* __restrict__ Wt,
    const int* __restrict__ nperm, const int* __restrict__ toff,
    const int* __restrict__ mt_t, const int* __restrict__ mt_m,
    const int* __restrict__ gcnt,
    unsigned short* __restrict__ kb, unsigned short* __restrict__ qb,
    unsigned short* __restrict__ vb) {
  int mtile = blockIdx.x;
  if (mtile >= gcnt[0]) return;
  int wave = threadIdx.x >> 6, lane = threadIdx.x & 63;
  int t = mt_t[mtile], tm = mt_m[mtile];
  int base = toff[t], cnt = toff[t + 1] - base;
  int lr = lane & 15, kq = lane >> 4;
  int arow = tm * 16 + lr;
  int node = nperm[base + (arow < cnt ? arow : cnt - 1)];
  const unsigned short* aptr = hb + node * 256 + kq * 8;
  bf16x8 af[8];
#pragma unroll
  for (int s = 0; s < 8; ++s) af[s] = *(const bf16x8*)(aptr + s * 32);
  int nd[4]; bool wr[4];
#pragma unroll
  for (int i = 0; i < 4; ++i) {
    int crow = tm * 16 + kq * 4 + i;
    wr[i] = crow < cnt;
    nd[i] = nperm[base + (wr[i] ? crow : 0)];
  }
  for (int j = 0; j < 12; ++j) {
    int tn = wave * 12 + j;
    const unsigned short* bptr = Wt + ((t * 768 + tn * 16 + lr) * 256) + kq * 8;
    f32x4 acc = {0.f, 0.f, 0.f, 0.f};
#pragma unroll
    for (int s = 0; s < 8; ++s)
      acc = mfma16(af[s], *(const bf16x8*)(bptr + s * 32), acc);
    int ccol = tn * 16 + lr;
#pragma unroll
    for (int i = 0; i < 4; ++i) {
      if (wr[i]) {
        unsigned short v = f2bf(acc[i]);
        if (ccol < 256)       kb[nd[i] * 256 + ccol] = v;
        else if (ccol < 512)  qb[nd[i] * 256 + (ccol - 256)] = v;
        else                  vb[nd[i] * 256 + (ccol - 512)] = v;
      }
    }
  }
}

// ---------------- K2: qt[bin] = q_dst^T A_r  (per (rel,dst) bin, MFMA) ----------------
__global__ __launch_bounds__(256) void k_qt(
    const unsigned short* __restrict__ qb, const unsigned short* __restrict__ Att,
    unsigned short* __restrict__ qt) {
  int dt = blockIdx.x;              // 1250 dst-tiles of 16
  int h = threadIdx.x >> 6, lane = threadIdx.x & 63;
  int lr = lane & 15, kq = lane >> 4;
  const unsigned short* ap = qb + (dt * 16 + lr) * 256 + h * 64 + kq * 8;
  bf16x8 a0 = *(const bf16x8*)ap;
  bf16x8 a1 = *(const bf16x8*)(ap + 32);
  for (int r = 0; r < NRL; ++r) {
    int rh = r * 4 + h;
#pragma unroll
    for (int tn = 0; tn < 4; ++tn) {
      const unsigned short* bp = Att + ((rh * 64 + tn * 16 + lr) * 64) + kq * 8;
      f32x4 acc = {0.f, 0.f, 0.f, 0.f};
      acc = mfma16(a0, *(const bf16x8*)bp, acc);
      acc = mfma16(a1, *(const bf16x8*)(bp + 32), acc);
#pragma unroll
      for (int i = 0; i < 4; ++i)
        qt[((size_t)r * NN + dt * 16 + kq * 4 + i) * 256 + h * 64 + tn * 16 + lr] =
            f2bf(acc[i]);
    }
  }
}

// ---------------- K3: mega — score+exp+denom+weighted-V+M-transform+reduce+normalize ----
__global__ __launch_bounds__(256) void k_mega(
    const int* __restrict__ boff, const int* __restrict__ je_src,
    const unsigned short* __restrict__ qt, const unsigned short* __restrict__ kb,
    const unsigned short* __restrict__ vb, const unsigned short* __restrict__ Mt,
    const float* __restrict__ pri, unsigned short* __restrict__ agg) {
  __shared__ float dsh[4][16];
  int dt = blockIdx.x;              // 1250 dst-tiles of 16
  int h = threadIdx.x >> 6, lane = threadIdx.x & 63;
  int lr = lane & 15, kq = lane >> 4;
  int dstA = dt * 16 + lr;
  f32x4 C[4] = {{0.f,0.f,0.f,0.f},{0.f,0.f,0.f,0.f},{0.f,0.f,0.f,0.f},{0.f,0.f,0.f,0.f}};
  float dtot = 0.f;
  for (int r = 0; r < NRL; ++r) {
    int bin = r * NN + dstA;
    int b0 = boff[bin], b1 = boff[bin + 1];
    float pscale = pri[r * 4 + h] * 0.125f;
    const unsigned short* qp = qt + (size_t)bin * 256 + h * 64 + kq * 8;
    bf16x8 qlo = *(const bf16x8*)qp;
    bf16x8 qhi = *(const bf16x8*)(qp + 32);
    float ql[8], qh[8];
#pragma unroll
    for (int m = 0; m < 8; ++m) {
      ql[m] = bf2f((unsigned short)qlo[m]);
      qh[m] = bf2f((unsigned short)qhi[m]);
    }
    float accl[8] = {0.f,0.f,0.f,0.f,0.f,0.f,0.f,0.f};
    float acch[8] = {0.f,0.f,0.f,0.f,0.f,0.f,0.f,0.f};
    float esum = 0.f;
    for (int j = b0; j < b1; ++j) {
      int src = je_src[j];
      const unsigned short* kp = kb + src * 256 + h * 64 + kq * 8;
      bf16x8 kl = *(const bf16x8*)kp;
      bf16x8 kh = *(const bf16x8*)(kp + 32);
      float s = 0.f;
#pragma unroll
      for (int m = 0; m < 8; ++m)
        s += ql[m] * bf2f((unsigned short)kl[m]) + qh[m] * bf2f((unsigned short)kh[m]);
      s += __shfl_xor(s, 16);
      s += __shfl_xor(s, 32);
      float ex = __expf(s * pscale);
      esum += ex;
      const unsigned short* vp = vb + src * 256 + h * 64 + kq * 8;
      bf16x8 vl = *(const bf16x8*)vp;
      bf16x8 vh = *(const bf16x8*)(vp + 32);
#pragma unroll
      for (int m = 0; m < 8; ++m) {
        accl[m] += ex * bf2f((unsigned short)vl[m]);
        acch[m] += ex * bf2f((unsigned short)vh[m]);
      }
    }
    dtot += esum;
    bf16x8 a0, a1;
#pragma unroll
    for (int m = 0; m < 8; ++m) {
      a0[m] = (short)f2bf(accl[m]);
      a1[m] = (short)f2bf(acch[m]);
    }
    int rh = r * 4 + h;
#pragma unroll
    for (int tn = 0; tn < 4; ++tn) {
      const unsigned short* bp = Mt + ((rh * 64 + tn * 16 + lr) * 64) + kq * 8;
      C[tn] = mfma16(a0, *(const bf16x8*)bp, C[tn]);
      C[tn] = mfma16(a1, *(const bf16x8*)(bp + 32), C[tn]);
    }
  }
  if (kq == 0) dsh[h][lr] = dtot;
  __syncthreads();
#pragma unroll
  for (int i = 0; i < 4; ++i) {
    float d = dsh[h][kq * 4 + i];
    float dinv = d > 0.f ? 1.f / d : 0.f;
#pragma unroll
    for (int tn = 0; tn < 4; ++tn)
      agg[(size_t)(dt * 16 + kq * 4 + i) * 256 + h * 64 + tn * 16 + lr] =
          f2bf(C[tn][i] * dinv);
  }
}

// ---------------- K4: final typed projection + sigmoid(skip) ----------------
__global__ __launch_bounds__(256) void k_gemm_out(
    const unsigned short* __restrict__ agg, const unsigned short* __restrict__ At,
    const int* __restrict__ nperm, const int* __restrict__ toff,
    const int* __restrict__ mt_t, const int* __restrict__ mt_m,
    const int* __restrict__ gcnt,
    const float* __restrict__ skip, float* __restrict__ out) {
  int mtile = blockIdx.x;
  if (mtile >= gcnt[0]) return;
  int wave = threadIdx.x >> 6, lane = threadIdx.x & 63;
  int t = mt_t[mtile], tm = mt_m[mtile];
  int base = toff[t], cnt = toff[t + 1] - base;
  int lr = lane & 15, kq = lane >> 4;
  int arow = tm * 16 + lr;
  int node = nperm[base + (arow < cnt ? arow : cnt - 1)];
  const unsigned short* aptr = agg + node * 256 + kq * 8;
  bf16x8 af[8];
#pragma unroll
  for (int s = 0; s < 8; ++s) af[s] = *(const bf16x8*)(aptr + s * 32);
  int nd[4]; bool wr[4];
#pragma unroll
  for (int i = 0; i < 4; ++i) {
    int crow = tm * 16 + kq * 4 + i;
    wr[i] = crow < cnt;
    nd[i] = nperm[base + (wr[i] ? crow : 0)];
  }
  float sg = 1.f / (1.f + __expf(-skip[t]));
  for (int j = 0; j < 4; ++j) {
    int tn = wave * 4 + j;
    const unsigned short* bptr = At + (t * 256 + tn * 16 + lr) * 256 + kq * 8;
    f32x4 acc = {0.f, 0.f, 0.f, 0.f};
#pragma unroll
    for (int s = 0; s < 8; ++s)
      acc = mfma16(af[s], *(const bf16x8*)(bptr + s * 32), acc);
    int ccol = tn * 16 + lr;
#pragma unroll
    for (int i = 0; i < 4; ++i)
      if (wr[i]) out[nd[i] * 256 + ccol] = acc[i] * sg;
  }
}

extern "C" void kernel_launch(void* const* d_in, const int* in_sizes, int n_in,
                              void* d_out, int out_size, void* d_ws, size_t ws_size,
                              hipStream_t stream) {
  (void)in_sizes; (void)n_in; (void)out_size; (void)ws_size;
  const float* h    = (const float*)d_in[0];
  const float* Wk   = (const float*)d_in[1];
  const float* Wq   = (const float*)d_in[2];
  const float* Wv   = (const float*)d_in[3];
  const float* Wa   = (const float*)d_in[4];
  const float* ratt = (const float*)d_in[5];
  const float* rmsg = (const float*)d_in[6];
  const float* pri  = (const float*)d_in[7];
  const float* skp  = (const float*)d_in[8];
  const int* ntype  = (const int*)d_in[9];
  const int* etyp   = (const int*)d_in[10];
  const int* rowi   = (const int*)d_in[11];
  const int* coli   = (const int*)d_in[12];
  float* out = (float*)d_out;

  char* p = (char*)d_ws;
  auto alloc = [&](size_t bytes) {
    void* q = (void*)p;
    p += (bytes + 255) & ~(size_t)255;
    return q;
  };
  unsigned short* hb  = (unsigned short*)alloc((size_t)NN * 256 * 2);
  unsigned short* Wt  = (unsigned short*)alloc((size_t)4 * 768 * 256 * 2);
  unsigned short* At  = (unsigned short*)alloc((size_t)4 * 256 * 256 * 2);
  unsigned short* Att = (unsigned short*)alloc((size_t)32 * 4096 * 2);
  unsigned short* Mt  = (unsigned short*)alloc((size_t)32 * 4096 * 2);
  unsigned short* kb  = (unsigned short*)alloc((size_t)NN * 256 * 2);
  unsigned short* qb  = (unsigned short*)alloc((size_t)NN * 256 * 2);
  unsigned short* vb  = (unsigned short*)alloc((size_t)NN * 256 * 2);
  unsigned short* qt  = (unsigned short*)alloc((size_t)NB * 256 * 2);
  unsigned short* agg = (unsigned short*)alloc((size_t)NN * 256 * 2);
  int* ncnt  = (int*)alloc(16);
  int* toff  = (int*)alloc(32);
  int* ncur  = (int*)alloc(16);
  int* nperm = (int*)alloc((size_t)NN * 4);
  int* bcnt  = (int*)alloc((size_t)NB * 4);
  int* boff  = (int*)alloc((size_t)(NB + 1) * 4);
  int* bcur  = (int*)alloc((size_t)NB * 4);
  int* psum  = (int*)alloc((size_t)625 * 4);
  int* je_src = (int*)alloc((size_t)NE * 4);
  int* mt_t = (int*)alloc((size_t)1253 * 4);
  int* mt_m = (int*)alloc((size_t)1253 * 4);
  int* gcnt = (int*)alloc(32);

  // init + prep
  k_init<<<(NB + 255) / 256, 256, 0, stream>>>(bcnt, ncnt);
  k_cast4<<<(NN * 64 + 255) / 256, 256, 0, stream>>>(h, hb, NN * 64);
  k_prep_wkqv<<<4 * 768, 256, 0, stream>>>(Wk, Wq, Wv, Wt);
  k_prep_a<<<4 * 256, 256, 0, stream>>>(Wa, At);
  k_prep_rel2<<<(32 * 4096 + 255) / 256, 256, 0, stream>>>(ratt, rmsg, Att, Mt);

  // counts / buckets / CSR
  k_count_all<<<(NE + 255) / 256, 256, 0, stream>>>(ntype, etyp, coli, ncnt, bcnt);
  k_meta<<<1, 256, 0, stream>>>(ncnt, toff, ncur, mt_t, mt_m, gcnt);
  k_nscatter<<<(NN + 255) / 256, 256, 0, stream>>>(ntype, ncur, nperm, NN);
  k_scan1<<<625, 256, 0, stream>>>(bcnt, boff, psum);
  k_scan2<<<1, 1024, 0, stream>>>(psum);
  k_scan3<<<625, 256, 0, stream>>>(boff, bcur, psum);
  k_escatter<<<(NE + 255) / 256, 256, 0, stream>>>(etyp, rowi, coli, bcur, je_src);

  // main pipeline
  k_gemm_kqv<<<1253, 256, 0, stream>>>(hb, Wt, nperm, toff, mt_t, mt_m, gcnt, kb, qb, vb);
  k_qt<<<1250, 256, 0, stream>>>(qb, Att, qt);
  k_mega<<<1250, 256, 0, stream>>>(boff, je_src, qt, kb, vb, Mt, pri, agg);
  k_gemm_out<<<1253, 256, 0, stream>>>(agg, At, nperm, toff, mt_t, mt_m, gcnt, skp, out);
}

// Round 5
// 541.060 us; speedup vs baseline: 1.6240x; 1.0251x over previous
//
#include <hip/hip_runtime.h>

static constexpr int NN  = 20000;
static constexpr int NE  = 320000;
static constexpr int NTY = 4;
static constexpr int NRL = 8;
static constexpr int NB  = NRL * NN;   // 160000 bins = (rel, dst)

typedef short bf16x8 __attribute__((ext_vector_type(8)));
typedef float f32x4  __attribute__((ext_vector_type(4)));
typedef unsigned short u16x4 __attribute__((ext_vector_type(4)));

__device__ __forceinline__ unsigned short f2bf(float f) {
  unsigned u = __float_as_uint(f);
  u += 0x7fffu + ((u >> 16) & 1u);
  return (unsigned short)(u >> 16);
}
__device__ __forceinline__ float bf2f(unsigned short b) {
  return __uint_as_float(((unsigned)b) << 16);
}
__device__ __forceinline__ f32x4 mfma16(bf16x8 a, bf16x8 b, f32x4 c) {
  return __builtin_amdgcn_mfma_f32_16x16x32_bf16(a, b, c, 0, 0, 0);
}

// ---------------- init / prep ----------------
__global__ void k_init(int* bcnt, int* ncnt, float* denom) {
  int i = blockIdx.x * 256 + threadIdx.x;
  if (i < NB) bcnt[i] = 0;
  if (i < NN * 4) denom[i] = 0.f;
  if (i < NTY) ncnt[i] = 0;
}
__global__ void k_cast4(const float* in, unsigned short* out, int n4) {
  int i = blockIdx.x * 256 + threadIdx.x;
  if (i >= n4) return;
  const float* p = in + i * 4;
  u16x4 o;
  o[0] = f2bf(p[0]); o[1] = f2bf(p[1]); o[2] = f2bf(p[2]); o[3] = f2bf(p[3]);
  *(u16x4*)(out + i * 4) = o;
}
// Wt[t][j][i] = W{k|q|v}[t][i][j]  (B^T layout), j in [0,768)
__global__ void k_prep_wkqv(const float* Wk, const float* Wq, const float* Wv,
                            unsigned short* Wt) {
  int j = blockIdx.x % 768, t = blockIdx.x / 768, i = threadIdx.x;
  const float* src; int c;
  if (j < 256)      { src = Wk; c = j; }
  else if (j < 512) { src = Wq; c = j - 256; }
  else              { src = Wv; c = j - 512; }
  Wt[(t * 768 + j) * 256 + i] = f2bf(src[(t * 256 + i) * 256 + c]);
}
__global__ void k_prep_a(const float* Wa, unsigned short* At) {
  int j = blockIdx.x % 256, t = blockIdx.x / 256, i = threadIdx.x;
  At[(t * 256 + j) * 256 + i] = f2bf(Wa[(t * 256 + i) * 256 + j]);
}
// Att[rh][e][d] = att[rh][d][e];  Mt[rh][e][d] = msg[rh][d][e]
__global__ void k_prep_rel2(const float* att, const float* msg,
                            unsigned short* Att, unsigned short* Mt) {
  int idx = blockIdx.x * 256 + threadIdx.x;
  if (idx >= 32 * 4096) return;
  int rh = idx >> 12, e = (idx >> 6) & 63, d = idx & 63;
  Att[idx] = f2bf(att[rh * 4096 + d * 64 + e]);
  Mt[idx]  = f2bf(msg[rh * 4096 + d * 64 + e]);
}

// ---------------- counts ----------------
__global__ void k_count_all(const int* ntype, const int* etyp, const int* coli,
                            int* ncnt, int* bcnt) {
  int i = blockIdx.x * 256 + threadIdx.x;
  if (i < NE) atomicAdd(&bcnt[etyp[i] * NN + coli[i]], 1);
  if (i < NN) atomicAdd(&ncnt[ntype[i]], 1);
}
// node-type scan + row-tile list
__global__ void k_meta(const int* ncnt, int* toff, int* ncur,
                       int* mt_t, int* mt_m, int* gcnt) {
  __shared__ int ts[5];
  if (threadIdx.x == 0) {
    int s = 0;
    for (int t = 0; t < NTY; ++t) { toff[t] = s; ncur[t] = s; s += ncnt[t]; }
    toff[NTY] = s;
    s = 0;
    for (int t = 0; t < NTY; ++t) { ts[t] = s; s += (ncnt[t] + 15) >> 4; }
    ts[4] = s; gcnt[0] = s;
  }
  __syncthreads();
  int nmt = ts[4];
  for (int i = threadIdx.x; i < nmt; i += 256) {
    int t = 0;
    while (t < 3 && i >= ts[t + 1]) ++t;
    mt_t[i] = t; mt_m[i] = i - ts[t];
  }
}
__global__ void k_nscatter(const int* key, int* cur, int* perm, int n) {
  int i = blockIdx.x * 256 + threadIdx.x;
  if (i < n) { int p = atomicAdd(&cur[key[i]], 1); perm[p] = i; }
}

// ---------------- bin scans ----------------
__global__ void k_scan1(const int* cnt, int* off, int* psum) {
  __shared__ int sm[256];
  int i = blockIdx.x * 256 + threadIdx.x;
  int v = cnt[i];
  sm[threadIdx.x] = v;
  __syncthreads();
  for (int d = 1; d < 256; d <<= 1) {
    int t = (threadIdx.x >= d) ? sm[threadIdx.x - d] : 0;
    __syncthreads();
    sm[threadIdx.x] += t;
    __syncthreads();
  }
  off[i] = sm[threadIdx.x] - v;
  if (threadIdx.x == 255) psum[blockIdx.x] = sm[255];
}
__global__ void k_scan2(int* psum) {
  __shared__ int sm[1024];
  int t = threadIdx.x;
  int v = (t < 625) ? psum[t] : 0;
  sm[t] = v;
  __syncthreads();
  for (int d = 1; d < 1024; d <<= 1) {
    int x = (t >= d) ? sm[t - d] : 0;
    __syncthreads();
    sm[t] += x;
    __syncthreads();
  }
  if (t < 625) psum[t] = sm[t] - v;
}
__global__ void k_scan3(int* off, int* cur, const int* psum) {
  int i = blockIdx.x * 256 + threadIdx.x;
  int v = off[i] + psum[blockIdx.x];
  off[i] = v; cur[i] = v;
  if (i == 0) off[NB] = NE;
}
__global__ void k_escatter(const int* etyp, const int* rowi, const int* coli,
                           int* cur, int* je_src) {
  int e = blockIdx.x * 256 + threadIdx.x;
  if (e >= NE) return;
  int bin = etyp[e] * NN + coli[e];
  int j = atomicAdd(&cur[bin], 1);
  je_src[j] = rowi[e];
}

// ---------------- K1: typed K/Q/V projection (k,v interleaved into kvb) -------------
__global__ __launch_bounds__(256) void k_gemm_kqv(
    const unsigned short* __restrict__ hb, const unsigned short* __restrict__ Wt,
    const int* __restrict__ nperm, const int* __restrict__ toff,
    const int* __restrict__ mt_t, const int* __restrict__ mt_m,
    const int* __restrict__ gcnt,
    unsigned short* __restrict__ kvb, unsigned short* __restrict__ qb) {
  int mtile = blockIdx.x;
  if (mtile >= gcnt[0]) return;
  int wave = threadIdx.x >> 6, lane = threadIdx.x & 63;
  int t = mt_t[mtile], tm = mt_m[mtile];
  int base = toff[t], cnt = toff[t + 1] - base;
  int lr = lane & 15, kq = lane >> 4;
  int arow = tm * 16 + lr;
  int node = nperm[base + (arow < cnt ? arow : cnt - 1)];
  const unsigned short* aptr = hb + node * 256 + kq * 8;
  bf16x8 af[8];
#pragma unroll
  for (int s = 0; s < 8; ++s) af[s] = *(const bf16x8*)(aptr + s * 32);
  int nd[4]; bool wr[4];
#pragma unroll
  for (int i = 0; i < 4; ++i) {
    int crow = tm * 16 + kq * 4 + i;
    wr[i] = crow < cnt;
    nd[i] = nperm[base + (wr[i] ? crow : 0)];
  }
  for (int j = 0; j < 12; ++j) {
    int tn = wave * 12 + j;
    const unsigned short* bptr = Wt + ((t * 768 + tn * 16 + lr) * 256) + kq * 8;
    f32x4 acc = {0.f, 0.f, 0.f, 0.f};
#pragma unroll
    for (int s = 0; s < 8; ++s)
      acc = mfma16(af[s], *(const bf16x8*)(bptr + s * 32), acc);
    int ccol = tn * 16 + lr;
#pragma unroll
    for (int i = 0; i < 4; ++i) {
      if (wr[i]) {
        unsigned short v = f2bf(acc[i]);
        if (ccol < 256)
          kvb[(size_t)nd[i] * 512 + (ccol >> 6) * 128 + (ccol & 63)] = v;
        else if (ccol < 512)
          qb[nd[i] * 256 + (ccol - 256)] = v;
        else {
          int c = ccol - 512;
          kvb[(size_t)nd[i] * 512 + (c >> 6) * 128 + 64 + (c & 63)] = v;
        }
      }
    }
  }
}

// ---------------- K2: mega — in-reg qt + score+exp+weighted-V+M-transform ----------
// block = (dst-tile of 16, relation-half of 4); wave = head
__global__ __launch_bounds__(256) void k_mega(
    const int* __restrict__ boff, const int* __restrict__ je_src,
    const unsigned short* __restrict__ qb, const unsigned short* __restrict__ kvb,
    const unsigned short* __restrict__ Att, const unsigned short* __restrict__ Mt,
    const float* __restrict__ pri, unsigned short* __restrict__ aggh,
    float* __restrict__ denom) {
  __shared__ unsigned short qsh[4][16][72];   // [head][dst][dim], +8 pad
  int dt = blockIdx.x >> 1, half = blockIdx.x & 1;
  int h = threadIdx.x >> 6, lane = threadIdx.x & 63;
  int lr = lane & 15, kq = lane >> 4;
  // q A-fragments: rows = the 16 dsts of this tile
  const unsigned short* ap = qb + (dt * 16 + lr) * 256 + h * 64 + kq * 8;
  bf16x8 aq0 = *(const bf16x8*)ap;
  bf16x8 aq1 = *(const bf16x8*)(ap + 32);
  f32x4 C[4] = {{0.f,0.f,0.f,0.f},{0.f,0.f,0.f,0.f},{0.f,0.f,0.f,0.f},{0.f,0.f,0.f,0.f}};
  float dtot = 0.f;
  for (int rr = 0; rr < 4; ++rr) {
    int r = half * 4 + rr;
    int rh = r * 4 + h;
    // qt[dst, d] = sum_e q[dst,e] * A_r[h][d,e]  (Att is [rh][e? no: rows d][e->d transp])
#pragma unroll
    for (int tn = 0; tn < 4; ++tn) {
      const unsigned short* bp = Att + ((rh * 64 + tn * 16 + lr) * 64) + kq * 8;
      f32x4 acc = {0.f, 0.f, 0.f, 0.f};
      acc = mfma16(aq0, *(const bf16x8*)bp, acc);
      acc = mfma16(aq1, *(const bf16x8*)(bp + 32), acc);
#pragma unroll
      for (int i = 0; i < 4; ++i)
        qsh[h][kq * 4 + i][tn * 16 + lr] = f2bf(acc[i]);  // transpose via LDS
    }
    // wave-local LDS round-trip: same wave writes then reads; compiler orders ds ops
    float ql[8], qh[8];
#pragma unroll
    for (int m = 0; m < 8; ++m) ql[m] = bf2f(qsh[h][lr][kq * 8 + m]);
#pragma unroll
    for (int m = 0; m < 8; ++m) qh[m] = bf2f(qsh[h][lr][32 + kq * 8 + m]);
    int bin = r * NN + dt * 16 + lr;
    int b0 = boff[bin], b1 = boff[bin + 1];
    float pscale = pri[rh] * 0.125f;
    float accl[8] = {0.f,0.f,0.f,0.f,0.f,0.f,0.f,0.f};
    float acch[8] = {0.f,0.f,0.f,0.f,0.f,0.f,0.f,0.f};
    float esum = 0.f;
    for (int j = b0; j < b1; ++j) {
      int src = je_src[j];
      const unsigned short* kp = kvb + (size_t)src * 512 + h * 128 + kq * 8;
      bf16x8 kl = *(const bf16x8*)kp;
      bf16x8 kh = *(const bf16x8*)(kp + 32);
      float s = 0.f;
#pragma unroll
      for (int m = 0; m < 8; ++m)
        s += ql[m] * bf2f((unsigned short)kl[m]) + qh[m] * bf2f((unsigned short)kh[m]);
      s += __shfl_xor(s, 16);
      s += __shfl_xor(s, 32);
      float ex = __expf(s * pscale);
      esum += ex;
      bf16x8 vl = *(const bf16x8*)(kp + 64);
      bf16x8 vh = *(const bf16x8*)(kp + 96);
#pragma unroll
      for (int m = 0; m < 8; ++m) {
        accl[m] += ex * bf2f((unsigned short)vl[m]);
        acch[m] += ex * bf2f((unsigned short)vh[m]);
      }
    }
    dtot += esum;
    bf16x8 a0, a1;
#pragma unroll
    for (int m = 0; m < 8; ++m) {
      a0[m] = (short)f2bf(accl[m]);
      a1[m] = (short)f2bf(acch[m]);
    }
#pragma unroll
    for (int tn = 0; tn < 4; ++tn) {
      const unsigned short* bp = Mt + ((rh * 64 + tn * 16 + lr) * 64) + kq * 8;
      C[tn] = mfma16(a0, *(const bf16x8*)bp, C[tn]);
      C[tn] = mfma16(a1, *(const bf16x8*)(bp + 32), C[tn]);
    }
  }
  if (kq == 0) atomicAdd(&denom[(dt * 16 + lr) * 4 + h], dtot);
#pragma unroll
  for (int tn = 0; tn < 4; ++tn)
#pragma unroll
    for (int i = 0; i < 4; ++i)
      aggh[((size_t)half * NN + dt * 16 + kq * 4 + i) * 256 + h * 64 + tn * 16 + lr] =
          f2bf(C[tn][i]);
}

// ---------------- K3: final typed projection + normalize + sigmoid(skip) ------------
__global__ __launch_bounds__(256) void k_gemm_out(
    const unsigned short* __restrict__ aggh, const float* __restrict__ denom,
    const unsigned short* __restrict__ At,
    const int* __restrict__ nperm, const int* __restrict__ toff,
    const int* __restrict__ mt_t, const int* __restrict__ mt_m,
    const int* __restrict__ gcnt,
    const float* __restrict__ skip, float* __restrict__ out) {
  int mtile = blockIdx.x;
  if (mtile >= gcnt[0]) return;
  int wave = threadIdx.x >> 6, lane = threadIdx.x & 63;
  int t = mt_t[mtile], tm = mt_m[mtile];
  int base = toff[t], cnt = toff[t + 1] - base;
  int lr = lane & 15, kq = lane >> 4;
  int arow = tm * 16 + lr;
  int node = nperm[base + (arow < cnt ? arow : cnt - 1)];
  float dn[4];
#pragma unroll
  for (int hh = 0; hh < 4; ++hh) {
    float d = denom[node * 4 + hh];
    dn[hh] = d > 0.f ? 1.f / d : 0.f;
  }
  const unsigned short* g0 = aggh + (size_t)node * 256 + kq * 8;
  const unsigned short* g1 = aggh + ((size_t)NN + node) * 256 + kq * 8;
  bf16x8 af[8];
#pragma unroll
  for (int s = 0; s < 8; ++s) {
    bf16x8 x0 = *(const bf16x8*)(g0 + s * 32);
    bf16x8 x1 = *(const bf16x8*)(g1 + s * 32);
    float dv = dn[(kq * 8 + s * 32) >> 6];
#pragma unroll
    for (int m = 0; m < 8; ++m)
      af[s][m] = (short)f2bf((bf2f((unsigned short)x0[m]) +
                              bf2f((unsigned short)x1[m])) * dv);
  }
  int nd[4]; bool wr[4];
#pragma unroll
  for (int i = 0; i < 4; ++i) {
    int crow = tm * 16 + kq * 4 + i;
    wr[i] = crow < cnt;
    nd[i] = nperm[base + (wr[i] ? crow : 0)];
  }
  float sg = 1.f / (1.f + __expf(-skip[t]));
  for (int j = 0; j < 4; ++j) {
    int tn = wave * 4 + j;
    const unsigned short* bptr = At + (t * 256 + tn * 16 + lr) * 256 + kq * 8;
    f32x4 acc = {0.f, 0.f, 0.f, 0.f};
#pragma unroll
    for (int s = 0; s < 8; ++s)
      acc = mfma16(af[s], *(const bf16x8*)(bptr + s * 32), acc);
    int ccol = tn * 16 + lr;
#pragma unroll
    for (int i = 0; i < 4; ++i)
      if (wr[i]) out[nd[i] * 256 + ccol] = acc[i] * sg;
  }
}

extern "C" void kernel_launch(void* const* d_in, const int* in_sizes, int n_in,
                              void* d_out, int out_size, void* d_ws, size_t ws_size,
                              hipStream_t stream) {
  (void)in_sizes; (void)n_in; (void)out_size; (void)ws_size;
  const float* h    = (const float*)d_in[0];
  const float* Wk   = (const float*)d_in[1];
  const float* Wq   = (const float*)d_in[2];
  const float* Wv   = (const float*)d_in[3];
  const float* Wa   = (const float*)d_in[4];
  const float* ratt = (const float*)d_in[5];
  const float* rmsg = (const float*)d_in[6];
  const float* pri  = (const float*)d_in[7];
  const float* skp  = (const float*)d_in[8];
  const int* ntype  = (const int*)d_in[9];
  const int* etyp   = (const int*)d_in[10];
  const int* rowi   = (const int*)d_in[11];
  const int* coli   = (const int*)d_in[12];
  float* out = (float*)d_out;

  char* p = (char*)d_ws;
  auto alloc = [&](size_t bytes) {
    void* q = (void*)p;
    p += (bytes + 255) & ~(size_t)255;
    return q;
  };
  unsigned short* hb   = (unsigned short*)alloc((size_t)NN * 256 * 2);
  unsigned short* Wt   = (unsigned short*)alloc((size_t)4 * 768 * 256 * 2);
  unsigned short* At   = (unsigned short*)alloc((size_t)4 * 256 * 256 * 2);
  unsigned short* Att  = (unsigned short*)alloc((size_t)32 * 4096 * 2);
  unsigned short* Mt   = (unsigned short*)alloc((size_t)32 * 4096 * 2);
  unsigned short* kvb  = (unsigned short*)alloc((size_t)NN * 512 * 2);
  unsigned short* qb   = (unsigned short*)alloc((size_t)NN * 256 * 2);
  unsigned short* aggh = (unsigned short*)alloc((size_t)2 * NN * 256 * 2);
  float* denom = (float*)alloc((size_t)NN * 4 * 4);
  int* ncnt  = (int*)alloc(16);
  int* toff  = (int*)alloc(32);
  int* ncur  = (int*)alloc(16);
  int* nperm = (int*)alloc((size_t)NN * 4);
  int* bcnt  = (int*)alloc((size_t)NB * 4);
  int* boff  = (int*)alloc((size_t)(NB + 1) * 4);
  int* bcur  = (int*)alloc((size_t)NB * 4);
  int* psum  = (int*)alloc((size_t)625 * 4);
  int* je_src = (int*)alloc((size_t)NE * 4);
  int* mt_t = (int*)alloc((size_t)1253 * 4);
  int* mt_m = (int*)alloc((size_t)1253 * 4);
  int* gcnt = (int*)alloc(32);

  // init + prep
  k_init<<<(NB + 255) / 256, 256, 0, stream>>>(bcnt, ncnt, denom);
  k_cast4<<<(NN * 64 + 255) / 256, 256, 0, stream>>>(h, hb, NN * 64);
  k_prep_wkqv<<<4 * 768, 256, 0, stream>>>(Wk, Wq, Wv, Wt);
  k_prep_a<<<4 * 256, 256, 0, stream>>>(Wa, At);
  k_prep_rel2<<<(32 * 4096 + 255) / 256, 256, 0, stream>>>(ratt, rmsg, Att, Mt);

  // counts / buckets / CSR
  k_count_all<<<(NE + 255) / 256, 256, 0, stream>>>(ntype, etyp, coli, ncnt, bcnt);
  k_meta<<<1, 256, 0, stream>>>(ncnt, toff, ncur, mt_t, mt_m, gcnt);
  k_nscatter<<<(NN + 255) / 256, 256, 0, stream>>>(ntype, ncur, nperm, NN);
  k_scan1<<<625, 256, 0, stream>>>(bcnt, boff, psum);
  k_scan2<<<1, 1024, 0, stream>>>(psum);
  k_scan3<<<625, 256, 0, stream>>>(boff, bcur, psum);
  k_escatter<<<(NE + 255) / 256, 256, 0, stream>>>(etyp, rowi, coli, bcur, je_src);

  // main pipeline
  k_gemm_kqv<<<1253, 256, 0, stream>>>(hb, Wt, nperm, toff, mt_t, mt_m, gcnt, kvb, qb);
  k_mega<<<2500, 256, 0, stream>>>(boff, je_src, qb, kvb, Att, Mt, pri, aggh, denom);
  k_gemm_out<<<1253, 256, 0, stream>>>(aggh, denom, At, nperm, toff, mt_t, mt_m, gcnt,
                                       skp, out);
}

// Round 6
// 438.425 us; speedup vs baseline: 2.0042x; 1.2341x over previous
//
#include <hip/hip_runtime.h>

static constexpr int NN  = 20000;
static constexpr int NE  = 320000;
static constexpr int NTY = 4;
static constexpr int NRL = 8;
static constexpr int NB  = NRL * NN;   // 160000 bins = (rel, perm-dst)

// prep-kernel segment sizes (blocks of 256)
static constexpr int ZB = (NB + NN * 4 + 255) / 256;  // 938
static constexpr int HB = NN * 64 / 256;              // 5000
static constexpr int WB = 4 * 768;                    // 3072
static constexpr int AB = 4 * 256;                    // 1024
static constexpr int RB = 32 * 4096 / 256;            // 512

typedef short bf16x8 __attribute__((ext_vector_type(8)));
typedef float f32x4  __attribute__((ext_vector_type(4)));
typedef unsigned short u16x4 __attribute__((ext_vector_type(4)));

__device__ __forceinline__ unsigned short f2bf(float f) {
  unsigned u = __float_as_uint(f);
  u += 0x7fffu + ((u >> 16) & 1u);
  return (unsigned short)(u >> 16);
}
__device__ __forceinline__ float bf2f(unsigned short b) {
  return __uint_as_float(((unsigned)b) << 16);
}
__device__ __forceinline__ f32x4 mfma16(bf16x8 a, bf16x8 b, f32x4 c) {
  return __builtin_amdgcn_mfma_f32_16x16x32_bf16(a, b, c, 0, 0, 0);
}

// ---------------- meta: count node types (self-contained) + scans + tile list -------
__global__ void k_meta(const int* __restrict__ ntype, int* toff, int* ncur,
                       int* mt_t, int* mt_m, int* gcnt) {
  __shared__ int c4[4];
  __shared__ int ts[5];
  if (threadIdx.x < 4) c4[threadIdx.x] = 0;
  __syncthreads();
  int l0 = 0, l1 = 0, l2 = 0, l3 = 0;
  for (int i = threadIdx.x; i < NN; i += 256) {
    int ty = ntype[i];
    l0 += (ty == 0); l1 += (ty == 1); l2 += (ty == 2); l3 += (ty == 3);
  }
  atomicAdd(&c4[0], l0); atomicAdd(&c4[1], l1);
  atomicAdd(&c4[2], l2); atomicAdd(&c4[3], l3);
  __syncthreads();
  if (threadIdx.x == 0) {
    int s = 0, s2 = 0;
    for (int t = 0; t < NTY; ++t) {
      toff[t] = s; ncur[t] = s; s += c4[t];
      ts[t] = s2; s2 += (c4[t] + 15) >> 4;
    }
    toff[NTY] = s; ts[NTY] = s2; gcnt[0] = s2;
  }
  __syncthreads();
  int nmt = ts[4];
  for (int i = threadIdx.x; i < nmt; i += 256) {
    int t = 0;
    while (t < 3 && i >= ts[t + 1]) ++t;
    mt_t[i] = t; mt_m[i] = i - ts[t];
  }
}
__global__ void k_nscatter(const int* __restrict__ key, int* cur,
                           int* nperm, int* inv) {
  int i = blockIdx.x * 256 + threadIdx.x;
  if (i < NN) {
    int p = atomicAdd(&cur[key[i]], 1);
    nperm[p] = i;
    inv[i] = p;
  }
}

// ---------------- fused prep: zero + h-cast(perm order) + weight transposes --------
__global__ void k_prep_all(const float* __restrict__ h, const float* __restrict__ Wk,
                           const float* __restrict__ Wq, const float* __restrict__ Wv,
                           const float* __restrict__ Wa, const float* __restrict__ ratt,
                           const float* __restrict__ rmsg, const int* __restrict__ nperm,
                           int* bcnt, float* denom,
                           unsigned short* hbp, unsigned short* Wt, unsigned short* At,
                           unsigned short* Att, unsigned short* Mt) {
  int b = blockIdx.x;
  if (b < ZB) {
    int i = b * 256 + threadIdx.x;
    if (i < NB) bcnt[i] = 0;
    else if (i < NB + NN * 4) denom[i - NB] = 0.f;
  } else if (b < ZB + HB) {
    int q = (b - ZB) * 256 + threadIdx.x;     // quad index over NN*64
    int p = q >> 6, c4 = q & 63;
    int node = nperm[p];
    const float* s = h + (size_t)node * 256 + c4 * 4;
    u16x4 o;
    o[0] = f2bf(s[0]); o[1] = f2bf(s[1]); o[2] = f2bf(s[2]); o[3] = f2bf(s[3]);
    *(u16x4*)(hbp + (size_t)p * 256 + c4 * 4) = o;
  } else if (b < ZB + HB + WB) {
    int bb = b - (ZB + HB);
    int j = bb % 768, t = bb / 768, i = threadIdx.x;
    const float* src; int c;
    if (j < 256)      { src = Wk; c = j; }
    else if (j < 512) { src = Wq; c = j - 256; }
    else              { src = Wv; c = j - 512; }
    Wt[(t * 768 + j) * 256 + i] = f2bf(src[(t * 256 + i) * 256 + c]);
  } else if (b < ZB + HB + WB + AB) {
    int bb = b - (ZB + HB + WB);
    int j = bb % 256, t = bb / 256, i = threadIdx.x;
    At[(t * 256 + j) * 256 + i] = f2bf(Wa[(t * 256 + i) * 256 + j]);
  } else {
    int idx = (b - (ZB + HB + WB + AB)) * 256 + threadIdx.x;
    int rh = idx >> 12, e = (idx >> 6) & 63, d = idx & 63;
    Att[idx] = f2bf(ratt[rh * 4096 + d * 64 + e]);
    Mt[idx]  = f2bf(rmsg[rh * 4096 + d * 64 + e]);
  }
}

// ---------------- edge CSR by (rel, perm-dst) ----------------
__global__ void k_bcount(const int* __restrict__ etyp, const int* __restrict__ coli,
                         const int* __restrict__ inv, int* bcnt) {
  int e = blockIdx.x * 256 + threadIdx.x;
  if (e < NE) atomicAdd(&bcnt[etyp[e] * NN + inv[coli[e]]], 1);
}
__global__ void k_scan1(const int* cnt, int* off, int* psum) {
  __shared__ int sm[256];
  int i = blockIdx.x * 256 + threadIdx.x;
  int v = cnt[i];
  sm[threadIdx.x] = v;
  __syncthreads();
  for (int d = 1; d < 256; d <<= 1) {
    int t = (threadIdx.x >= d) ? sm[threadIdx.x - d] : 0;
    __syncthreads();
    sm[threadIdx.x] += t;
    __syncthreads();
  }
  off[i] = sm[threadIdx.x] - v;
  if (threadIdx.x == 255) psum[blockIdx.x] = sm[255];
}
__global__ void k_scan2(int* psum) {
  __shared__ int sm[1024];
  int t = threadIdx.x;
  int v = (t < 625) ? psum[t] : 0;
  sm[t] = v;
  __syncthreads();
  for (int d = 1; d < 1024; d <<= 1) {
    int x = (t >= d) ? sm[t - d] : 0;
    __syncthreads();
    sm[t] += x;
    __syncthreads();
  }
  if (t < 625) psum[t] = sm[t] - v;
}
__global__ void k_scan3(int* off, int* cur, const int* psum) {
  int i = blockIdx.x * 256 + threadIdx.x;
  int v = off[i] + psum[blockIdx.x];
  off[i] = v; cur[i] = v;
  if (i == 0) off[NB] = NE;
}
__global__ void k_escatter(const int* __restrict__ etyp, const int* __restrict__ rowi,
                           const int* __restrict__ coli, const int* __restrict__ inv,
                           int* cur, int* je_src) {
  int e = blockIdx.x * 256 + threadIdx.x;
  if (e >= NE) return;
  int bin = etyp[e] * NN + inv[coli[e]];
  int j = atomicAdd(&cur[bin], 1);
  je_src[j] = inv[rowi[e]];
}

// ---------------- K1: typed K/Q/V projection (perm space, coalesced) ----------------
__global__ __launch_bounds__(256) void k_gemm_kqv(
    const unsigned short* __restrict__ hbp, const unsigned short* __restrict__ Wt,
    const int* __restrict__ toff, const int* __restrict__ mt_t,
    const int* __restrict__ mt_m, const int* __restrict__ gcnt,
    unsigned short* __restrict__ kvb, unsigned short* __restrict__ qb) {
  int mtile = blockIdx.x;
  if (mtile >= gcnt[0]) return;
  int wave = threadIdx.x >> 6, lane = threadIdx.x & 63;
  int t = mt_t[mtile], tm = mt_m[mtile];
  int base = toff[t], cnt = toff[t + 1] - base;
  int lr = lane & 15, kq = lane >> 4;
  int arow = tm * 16 + lr;
  int prow = base + (arow < cnt ? arow : cnt - 1);
  const unsigned short* aptr = hbp + (size_t)prow * 256 + kq * 8;
  bf16x8 af[8];
#pragma unroll
  for (int s = 0; s < 8; ++s) af[s] = *(const bf16x8*)(aptr + s * 32);
  int pr[4]; bool wr[4];
#pragma unroll
  for (int i = 0; i < 4; ++i) {
    int crow = tm * 16 + kq * 4 + i;
    wr[i] = crow < cnt;
    pr[i] = base + (wr[i] ? crow : 0);
  }
  for (int j = 0; j < 12; ++j) {
    int tn = wave * 12 + j;
    const unsigned short* bptr = Wt + ((t * 768 + tn * 16 + lr) * 256) + kq * 8;
    f32x4 acc = {0.f, 0.f, 0.f, 0.f};
#pragma unroll
    for (int s = 0; s < 8; ++s)
      acc = mfma16(af[s], *(const bf16x8*)(bptr + s * 32), acc);
    int ccol = tn * 16 + lr;
#pragma unroll
    for (int i = 0; i < 4; ++i) {
      if (wr[i]) {
        unsigned short v = f2bf(acc[i]);
        if (ccol < 256)
          kvb[(size_t)pr[i] * 512 + (ccol >> 6) * 128 + (ccol & 63)] = v;
        else if (ccol < 512)
          qb[(size_t)pr[i] * 256 + (ccol - 256)] = v;
        else {
          int c = ccol - 512;
          kvb[(size_t)pr[i] * 512 + (c >> 6) * 128 + 64 + (c & 63)] = v;
        }
      }
    }
  }
}

// ---------------- K2: mega — in-reg qt + 2-wide edge loop + M-transform -------------
// block = (perm-dst-tile of 16, relation-half of 4); wave = head
__global__ __launch_bounds__(256) void k_mega(
    const int* __restrict__ boff, const int* __restrict__ je_src,
    const unsigned short* __restrict__ qb, const unsigned short* __restrict__ kvb,
    const unsigned short* __restrict__ Att, const unsigned short* __restrict__ Mt,
    const float* __restrict__ pri, unsigned short* __restrict__ aggh,
    float* __restrict__ denom) {
  __shared__ unsigned short qsh[4][16][72];   // [head][dst][dim], +8 pad
  int dt = blockIdx.x >> 1, half = blockIdx.x & 1;
  int h = threadIdx.x >> 6, lane = threadIdx.x & 63;
  int lr = lane & 15, kq = lane >> 4;
  const unsigned short* ap = qb + (size_t)(dt * 16 + lr) * 256 + h * 64 + kq * 8;
  bf16x8 aq0 = *(const bf16x8*)ap;
  bf16x8 aq1 = *(const bf16x8*)(ap + 32);
  f32x4 C[4] = {{0.f,0.f,0.f,0.f},{0.f,0.f,0.f,0.f},{0.f,0.f,0.f,0.f},{0.f,0.f,0.f,0.f}};
  float dtot = 0.f;
  for (int rr = 0; rr < 4; ++rr) {
    int r = half * 4 + rr;
    int rh = r * 4 + h;
    // qt[dst, d] = sum_e q[dst,e] * A_r[h][d,e]  (MFMA; transpose via wave-private LDS)
#pragma unroll
    for (int tn = 0; tn < 4; ++tn) {
      const unsigned short* bp = Att + ((rh * 64 + tn * 16 + lr) * 64) + kq * 8;
      f32x4 acc = {0.f, 0.f, 0.f, 0.f};
      acc = mfma16(aq0, *(const bf16x8*)bp, acc);
      acc = mfma16(aq1, *(const bf16x8*)(bp + 32), acc);
#pragma unroll
      for (int i = 0; i < 4; ++i)
        qsh[h][kq * 4 + i][tn * 16 + lr] = f2bf(acc[i]);
    }
    float ql[8], qh[8];
#pragma unroll
    for (int m = 0; m < 8; ++m) ql[m] = bf2f(qsh[h][lr][kq * 8 + m]);
#pragma unroll
    for (int m = 0; m < 8; ++m) qh[m] = bf2f(qsh[h][lr][32 + kq * 8 + m]);
    int bin = r * NN + dt * 16 + lr;
    int b0 = boff[bin], b1 = boff[bin + 1];
    float pscale = pri[rh] * 0.125f;
    float accl[8] = {0.f,0.f,0.f,0.f,0.f,0.f,0.f,0.f};
    float acch[8] = {0.f,0.f,0.f,0.f,0.f,0.f,0.f,0.f};
    float esum = 0.f;
    int j = b0;
    // 2-wide: 8 independent 16B gathers in flight per lane
    while (j + 2 <= b1) {
      int sA = je_src[j], sB = je_src[j + 1];
      const unsigned short* pA = kvb + (size_t)sA * 512 + h * 128 + kq * 8;
      const unsigned short* pB = kvb + (size_t)sB * 512 + h * 128 + kq * 8;
      bf16x8 kAl = *(const bf16x8*)pA,        kAh = *(const bf16x8*)(pA + 32);
      bf16x8 kBl = *(const bf16x8*)pB,        kBh = *(const bf16x8*)(pB + 32);
      bf16x8 vAl = *(const bf16x8*)(pA + 64), vAh = *(const bf16x8*)(pA + 96);
      bf16x8 vBl = *(const bf16x8*)(pB + 64), vBh = *(const bf16x8*)(pB + 96);
      float sa = 0.f, sb = 0.f;
#pragma unroll
      for (int m = 0; m < 8; ++m) {
        sa += ql[m] * bf2f((unsigned short)kAl[m]) + qh[m] * bf2f((unsigned short)kAh[m]);
        sb += ql[m] * bf2f((unsigned short)kBl[m]) + qh[m] * bf2f((unsigned short)kBh[m]);
      }
      sa += __shfl_xor(sa, 16); sa += __shfl_xor(sa, 32);
      sb += __shfl_xor(sb, 16); sb += __shfl_xor(sb, 32);
      float exA = __expf(sa * pscale), exB = __expf(sb * pscale);
      esum += exA + exB;
#pragma unroll
      for (int m = 0; m < 8; ++m) {
        accl[m] += exA * bf2f((unsigned short)vAl[m]) + exB * bf2f((unsigned short)vBl[m]);
        acch[m] += exA * bf2f((unsigned short)vAh[m]) + exB * bf2f((unsigned short)vBh[m]);
      }
      j += 2;
    }
    if (j < b1) {
      int sA = je_src[j];
      const unsigned short* pA = kvb + (size_t)sA * 512 + h * 128 + kq * 8;
      bf16x8 kAl = *(const bf16x8*)pA,        kAh = *(const bf16x8*)(pA + 32);
      bf16x8 vAl = *(const bf16x8*)(pA + 64), vAh = *(const bf16x8*)(pA + 96);
      float sa = 0.f;
#pragma unroll
      for (int m = 0; m < 8; ++m)
        sa += ql[m] * bf2f((unsigned short)kAl[m]) + qh[m] * bf2f((unsigned short)kAh[m]);
      sa += __shfl_xor(sa, 16); sa += __shfl_xor(sa, 32);
      float exA = __expf(sa * pscale);
      esum += exA;
#pragma unroll
      for (int m = 0; m < 8; ++m) {
        accl[m] += exA * bf2f((unsigned short)vAl[m]);
        acch[m] += exA * bf2f((unsigned short)vAh[m]);
      }
    }
    dtot += esum;
    bf16x8 a0, a1;
#pragma unroll
    for (int m = 0; m < 8; ++m) {
      a0[m] = (short)f2bf(accl[m]);
      a1[m] = (short)f2bf(acch[m]);
    }
#pragma unroll
    for (int tn = 0; tn < 4; ++tn) {
      const unsigned short* bp = Mt + ((rh * 64 + tn * 16 + lr) * 64) + kq * 8;
      C[tn] = mfma16(a0, *(const bf16x8*)bp, C[tn]);
      C[tn] = mfma16(a1, *(const bf16x8*)(bp + 32), C[tn]);
    }
  }
  if (kq == 0) atomicAdd(&denom[(dt * 16 + lr) * 4 + h], dtot);
#pragma unroll
  for (int tn = 0; tn < 4; ++tn)
#pragma unroll
    for (int i = 0; i < 4; ++i)
      aggh[((size_t)half * NN + dt * 16 + kq * 4 + i) * 256 + h * 64 + tn * 16 + lr] =
          f2bf(C[tn][i]);
}

// ---------------- K3: final typed projection + normalize + sigmoid(skip) ------------
__global__ __launch_bounds__(256) void k_gemm_out(
    const unsigned short* __restrict__ aggh, const float* __restrict__ denom,
    const unsigned short* __restrict__ At,
    const int* __restrict__ nperm, const int* __restrict__ toff,
    const int* __restrict__ mt_t, const int* __restrict__ mt_m,
    const int* __restrict__ gcnt,
    const float* __restrict__ skip, float* __restrict__ out) {
  int mtile = blockIdx.x;
  if (mtile >= gcnt[0]) return;
  int wave = threadIdx.x >> 6, lane = threadIdx.x & 63;
  int t = mt_t[mtile], tm = mt_m[mtile];
  int base = toff[t], cnt = toff[t + 1] - base;
  int lr = lane & 15, kq = lane >> 4;
  int arow = tm * 16 + lr;
  int prow = base + (arow < cnt ? arow : cnt - 1);
  float dn[4];
#pragma unroll
  for (int hh = 0; hh < 4; ++hh) {
    float d = denom[prow * 4 + hh];
    dn[hh] = d > 0.f ? 1.f / d : 0.f;
  }
  const unsigned short* g0 = aggh + (size_t)prow * 256 + kq * 8;
  const unsigned short* g1 = g0 + (size_t)NN * 256;
  bf16x8 af[8];
#pragma unroll
  for (int s = 0; s < 8; ++s) {
    bf16x8 x0 = *(const bf16x8*)(g0 + s * 32);
    bf16x8 x1 = *(const bf16x8*)(g1 + s * 32);
    float dv = dn[(kq * 8 + s * 32) >> 6];
#pragma unroll
    for (int m = 0; m < 8; ++m)
      af[s][m] = (short)f2bf((bf2f((unsigned short)x0[m]) +
                              bf2f((unsigned short)x1[m])) * dv);
  }
  int nd[4]; bool wr[4];
#pragma unroll
  for (int i = 0; i < 4; ++i) {
    int crow = tm * 16 + kq * 4 + i;
    wr[i] = crow < cnt;
    nd[i] = nperm[base + (wr[i] ? crow : 0)];
  }
  float sg = 1.f / (1.f + __expf(-skip[t]));
  for (int j = 0; j < 4; ++j) {
    int tn = wave * 4 + j;
    const unsigned short* bptr = At + (t * 256 + tn * 16 + lr) * 256 + kq * 8;
    f32x4 acc = {0.f, 0.f, 0.f, 0.f};
#pragma unroll
    for (int s = 0; s < 8; ++s)
      acc = mfma16(af[s], *(const bf16x8*)(bptr + s * 32), acc);
    int ccol = tn * 16 + lr;
#pragma unroll
    for (int i = 0; i < 4; ++i)
      if (wr[i]) out[nd[i] * 256 + ccol] = acc[i] * sg;
  }
}

extern "C" void kernel_launch(void* const* d_in, const int* in_sizes, int n_in,
                              void* d_out, int out_size, void* d_ws, size_t ws_size,
                              hipStream_t stream) {
  (void)in_sizes; (void)n_in; (void)out_size; (void)ws_size;
  const float* h    = (const float*)d_in[0];
  const float* Wk   = (const float*)d_in[1];
  const float* Wq   = (const float*)d_in[2];
  const float* Wv   = (const float*)d_in[3];
  const float* Wa   = (const float*)d_in[4];
  const float* ratt = (const float*)d_in[5];
  const float* rmsg = (const float*)d_in[6];
  const float* pri  = (const float*)d_in[7];
  const float* skp  = (const float*)d_in[8];
  const int* ntype  = (const int*)d_in[9];
  const int* etyp   = (const int*)d_in[10];
  const int* rowi   = (const int*)d_in[11];
  const int* coli   = (const int*)d_in[12];
  float* out = (float*)d_out;

  char* p = (char*)d_ws;
  auto alloc = [&](size_t bytes) {
    void* q = (void*)p;
    p += (bytes + 255) & ~(size_t)255;
    return q;
  };
  unsigned short* hbp  = (unsigned short*)alloc((size_t)NN * 256 * 2);
  unsigned short* Wt   = (unsigned short*)alloc((size_t)4 * 768 * 256 * 2);
  unsigned short* At   = (unsigned short*)alloc((size_t)4 * 256 * 256 * 2);
  unsigned short* Att  = (unsigned short*)alloc((size_t)32 * 4096 * 2);
  unsigned short* Mt   = (unsigned short*)alloc((size_t)32 * 4096 * 2);
  unsigned short* kvb  = (unsigned short*)alloc((size_t)NN * 512 * 2);
  unsigned short* qb   = (unsigned short*)alloc((size_t)NN * 256 * 2);
  unsigned short* aggh = (unsigned short*)alloc((size_t)2 * NN * 256 * 2);
  float* denom = (float*)alloc((size_t)NN * 4 * 4);
  int* toff  = (int*)alloc(32);
  int* ncur  = (int*)alloc(16);
  int* nperm = (int*)alloc((size_t)NN * 4);
  int* inv   = (int*)alloc((size_t)NN * 4);
  int* bcnt  = (int*)alloc((size_t)NB * 4);
  int* boff  = (int*)alloc((size_t)(NB + 1) * 4);
  int* bcur  = (int*)alloc((size_t)NB * 4);
  int* psum  = (int*)alloc((size_t)625 * 4);
  int* je_src = (int*)alloc((size_t)NE * 4);
  int* mt_t = (int*)alloc((size_t)1253 * 4);
  int* mt_m = (int*)alloc((size_t)1253 * 4);
  int* gcnt = (int*)alloc(32);

  // node buckets (perm space)
  k_meta<<<1, 256, 0, stream>>>(ntype, toff, ncur, mt_t, mt_m, gcnt);
  k_nscatter<<<(NN + 255) / 256, 256, 0, stream>>>(ntype, ncur, nperm, inv);

  // fused prep (zero + h-cast-perm + weight transposes)
  k_prep_all<<<ZB + HB + WB + AB + RB, 256, 0, stream>>>(
      h, Wk, Wq, Wv, Wa, ratt, rmsg, nperm, bcnt, denom, hbp, Wt, At, Att, Mt);

  // edge CSR by (rel, perm-dst)
  k_bcount<<<(NE + 255) / 256, 256, 0, stream>>>(etyp, coli, inv, bcnt);
  k_scan1<<<625, 256, 0, stream>>>(bcnt, boff, psum);
  k_scan2<<<1, 1024, 0, stream>>>(psum);
  k_scan3<<<625, 256, 0, stream>>>(boff, bcur, psum);
  k_escatter<<<(NE + 255) / 256, 256, 0, stream>>>(etyp, rowi, coli, inv, bcur, je_src);

  // main pipeline
  k_gemm_kqv<<<1253, 256, 0, stream>>>(hbp, Wt, toff, mt_t, mt_m, gcnt, kvb, qb);
  k_mega<<<2500, 256, 0, stream>>>(boff, je_src, qb, kvb, Att, Mt, pri, aggh, denom);
  k_gemm_out<<<1253, 256, 0, stream>>>(aggh, denom, At, nperm, toff, mt_t, mt_m, gcnt,
                                       skp, out);
}

// Round 7
// 432.934 us; speedup vs baseline: 2.0296x; 1.0127x over previous
//
#include <hip/hip_runtime.h>

static constexpr int NN  = 20000;
static constexpr int NE  = 320000;
static constexpr int NTY = 4;
static constexpr int NRL = 8;
static constexpr int NB  = NRL * NN;   // 160000 bins = (rel, perm-dst)

// prep-kernel segment sizes (blocks of 256)
static constexpr int ZB = (NB + NN * 4 + 255) / 256;  // 938
static constexpr int HB = NN * 64 / 256;              // 5000
static constexpr int WB = 4 * 768;                    // 3072
static constexpr int AB = 4 * 256;                    // 1024
static constexpr int RB = 32 * 4096 / 256;            // 512
static constexpr int CB = (NN + 255) / 256;           // 79 (type-count blocks)

typedef short bf16x8 __attribute__((ext_vector_type(8)));
typedef float f32x4  __attribute__((ext_vector_type(4)));
typedef unsigned short u16x4 __attribute__((ext_vector_type(4)));

__device__ __forceinline__ unsigned short f2bf(float f) {
  unsigned u = __float_as_uint(f);
  u += 0x7fffu + ((u >> 16) & 1u);
  return (unsigned short)(u >> 16);
}
__device__ __forceinline__ float bf2f(unsigned short b) {
  return __uint_as_float(((unsigned)b) << 16);
}
__device__ __forceinline__ f32x4 mfma16(bf16x8 a, bf16x8 b, f32x4 c) {
  return __builtin_amdgcn_mfma_f32_16x16x32_bf16(a, b, c, 0, 0, 0);
}

// ---------------- node-type counting (parallel partials, no pre-zero needed) -------
__global__ void k_tcount(const int* __restrict__ ntype, int* __restrict__ c4p) {
  __shared__ int c[4];
  if (threadIdx.x < 4) c[threadIdx.x] = 0;
  __syncthreads();
  int i = blockIdx.x * 256 + threadIdx.x;
  if (i < NN) atomicAdd(&c[ntype[i]], 1);
  __syncthreads();
  if (threadIdx.x < 4) c4p[blockIdx.x * 4 + threadIdx.x] = c[threadIdx.x];
}
__global__ void k_meta(const int* __restrict__ c4p, int* toff, int* ncur,
                       int* mt_t, int* mt_m, int* gcnt) {
  __shared__ int c4[4];
  __shared__ int ts[5];
  if (threadIdx.x < 4) {
    int s = 0;
    for (int b = 0; b < CB; ++b) s += c4p[b * 4 + threadIdx.x];
    c4[threadIdx.x] = s;
  }
  __syncthreads();
  if (threadIdx.x == 0) {
    int s = 0, s2 = 0;
    for (int t = 0; t < NTY; ++t) {
      toff[t] = s; ncur[t] = s; s += c4[t];
      ts[t] = s2; s2 += (c4[t] + 15) >> 4;
    }
    toff[NTY] = s; ts[NTY] = s2; gcnt[0] = s2;
  }
  __syncthreads();
  int nmt = ts[4];
  for (int i = threadIdx.x; i < nmt; i += 256) {
    int t = 0;
    while (t < 3 && i >= ts[t + 1]) ++t;
    mt_t[i] = t; mt_m[i] = i - ts[t];
  }
}
__global__ void k_nscatter(const int* __restrict__ key, int* cur,
                           int* nperm, int* inv) {
  int i = blockIdx.x * 256 + threadIdx.x;
  if (i < NN) {
    int p = atomicAdd(&cur[key[i]], 1);
    nperm[p] = i;
    inv[i] = p;
  }
}

// ---------------- fused prep: zero + h-cast(perm order) + weight transposes --------
__global__ void k_prep_all(const float* __restrict__ h, const float* __restrict__ Wk,
                           const float* __restrict__ Wq, const float* __restrict__ Wv,
                           const float* __restrict__ Wa, const float* __restrict__ ratt,
                           const float* __restrict__ rmsg, const int* __restrict__ nperm,
                           int* bcnt, float* denom,
                           unsigned short* hbp, unsigned short* Wt, unsigned short* At,
                           unsigned short* Att, unsigned short* Mt) {
  int b = blockIdx.x;
  if (b < ZB) {
    int i = b * 256 + threadIdx.x;
    if (i < NB) bcnt[i] = 0;
    else if (i < NB + NN * 4) denom[i - NB] = 0.f;
  } else if (b < ZB + HB) {
    int q = (b - ZB) * 256 + threadIdx.x;     // quad index over NN*64
    int p = q >> 6, c4 = q & 63;
    int node = nperm[p];
    const float* s = h + (size_t)node * 256 + c4 * 4;
    u16x4 o;
    o[0] = f2bf(s[0]); o[1] = f2bf(s[1]); o[2] = f2bf(s[2]); o[3] = f2bf(s[3]);
    *(u16x4*)(hbp + (size_t)p * 256 + c4 * 4) = o;
  } else if (b < ZB + HB + WB) {
    int bb = b - (ZB + HB);
    int j = bb % 768, t = bb / 768, i = threadIdx.x;
    const float* src; int c;
    if (j < 256)      { src = Wk; c = j; }
    else if (j < 512) { src = Wq; c = j - 256; }
    else              { src = Wv; c = j - 512; }
    Wt[(t * 768 + j) * 256 + i] = f2bf(src[(t * 256 + i) * 256 + c]);
  } else if (b < ZB + HB + WB + AB) {
    int bb = b - (ZB + HB + WB);
    int j = bb % 256, t = bb / 256, i = threadIdx.x;
    At[(t * 256 + j) * 256 + i] = f2bf(Wa[(t * 256 + i) * 256 + j]);
  } else {
    int idx = (b - (ZB + HB + WB + AB)) * 256 + threadIdx.x;
    int rh = idx >> 12, e = (idx >> 6) & 63, d = idx & 63;
    Att[idx] = f2bf(ratt[rh * 4096 + d * 64 + e]);
    Mt[idx]  = f2bf(rmsg[rh * 4096 + d * 64 + e]);
  }
}

// ---------------- edge CSR by (rel, perm-dst) ----------------
__global__ void k_bcount(const int* __restrict__ etyp, const int* __restrict__ coli,
                         const int* __restrict__ inv, int* bcnt) {
  int e = blockIdx.x * 256 + threadIdx.x;
  if (e < NE) atomicAdd(&bcnt[etyp[e] * NN + inv[coli[e]]], 1);
}
__global__ void k_scan1(const int* cnt, int* off, int* psum) {
  __shared__ int sm[256];
  int i = blockIdx.x * 256 + threadIdx.x;
  int v = cnt[i];
  sm[threadIdx.x] = v;
  __syncthreads();
  for (int d = 1; d < 256; d <<= 1) {
    int t = (threadIdx.x >= d) ? sm[threadIdx.x - d] : 0;
    __syncthreads();
    sm[threadIdx.x] += t;
    __syncthreads();
  }
  off[i] = sm[threadIdx.x] - v;
  if (threadIdx.x == 255) psum[blockIdx.x] = sm[255];
}
__global__ void k_scan2(int* psum) {
  __shared__ int sm[1024];
  int t = threadIdx.x;
  int v = (t < 625) ? psum[t] : 0;
  sm[t] = v;
  __syncthreads();
  for (int d = 1; d < 1024; d <<= 1) {
    int x = (t >= d) ? sm[t - d] : 0;
    __syncthreads();
    sm[t] += x;
    __syncthreads();
  }
  if (t < 625) psum[t] = sm[t] - v;
}
__global__ void k_scan3(int* off, int* cur, const int* psum) {
  int i = blockIdx.x * 256 + threadIdx.x;
  int v = off[i] + psum[blockIdx.x];
  off[i] = v; cur[i] = v;
  if (i == 0) off[NB] = NE;
}
__global__ void k_escatter(const int* __restrict__ etyp, const int* __restrict__ rowi,
                           const int* __restrict__ coli, const int* __restrict__ inv,
                           int* cur, int* je_src) {
  int e = blockIdx.x * 256 + threadIdx.x;
  if (e >= NE) return;
  int bin = etyp[e] * NN + inv[coli[e]];
  int j = atomicAdd(&cur[bin], 1);
  je_src[j] = inv[rowi[e]];
}

// ---------------- K1: typed K/Q/V projection (perm space, coalesced) ----------------
__global__ __launch_bounds__(256) void k_gemm_kqv(
    const unsigned short* __restrict__ hbp, const unsigned short* __restrict__ Wt,
    const int* __restrict__ toff, const int* __restrict__ mt_t,
    const int* __restrict__ mt_m, const int* __restrict__ gcnt,
    unsigned short* __restrict__ kvb, unsigned short* __restrict__ qb) {
  int mtile = blockIdx.x;
  if (mtile >= gcnt[0]) return;
  int wave = threadIdx.x >> 6, lane = threadIdx.x & 63;
  int t = mt_t[mtile], tm = mt_m[mtile];
  int base = toff[t], cnt = toff[t + 1] - base;
  int lr = lane & 15, kq = lane >> 4;
  int arow = tm * 16 + lr;
  int prow = base + (arow < cnt ? arow : cnt - 1);
  const unsigned short* aptr = hbp + (size_t)prow * 256 + kq * 8;
  bf16x8 af[8];
#pragma unroll
  for (int s = 0; s < 8; ++s) af[s] = *(const bf16x8*)(aptr + s * 32);
  int pr[4]; bool wr[4];
#pragma unroll
  for (int i = 0; i < 4; ++i) {
    int crow = tm * 16 + kq * 4 + i;
    wr[i] = crow < cnt;
    pr[i] = base + (wr[i] ? crow : 0);
  }
  for (int j = 0; j < 12; ++j) {
    int tn = wave * 12 + j;
    const unsigned short* bptr = Wt + ((t * 768 + tn * 16 + lr) * 256) + kq * 8;
    f32x4 acc = {0.f, 0.f, 0.f, 0.f};
#pragma unroll
    for (int s = 0; s < 8; ++s)
      acc = mfma16(af[s], *(const bf16x8*)(bptr + s * 32), acc);
    int ccol = tn * 16 + lr;
#pragma unroll
    for (int i = 0; i < 4; ++i) {
      if (wr[i]) {
        unsigned short v = f2bf(acc[i]);
        if (ccol < 256)
          kvb[(size_t)pr[i] * 512 + (ccol >> 6) * 128 + (ccol & 63)] = v;
        else if (ccol < 512)
          qb[(size_t)pr[i] * 256 + (ccol - 256)] = v;
        else {
          int c = ccol - 512;
          kvb[(size_t)pr[i] * 512 + (c >> 6) * 128 + 64 + (c & 63)] = v;
        }
      }
    }
  }
}

// ---------------- K2: mega — 2 rels/block, in-reg qt, 2-wide edge loop --------------
// block = (perm-dst-tile of 16, relation-quarter); wave = head
__global__ __launch_bounds__(256) void k_mega(
    const int* __restrict__ boff, const int* __restrict__ je_src,
    const unsigned short* __restrict__ qb, const unsigned short* __restrict__ kvb,
    const unsigned short* __restrict__ Att, const unsigned short* __restrict__ Mt,
    const float* __restrict__ pri, unsigned short* __restrict__ aggh,
    float* __restrict__ denom) {
  __shared__ unsigned short qsh[4][16][72];   // [head][dst][dim], +8 pad
  int dt = blockIdx.x >> 2, quarter = blockIdx.x & 3;
  int h = threadIdx.x >> 6, lane = threadIdx.x & 63;
  int lr = lane & 15, kq = lane >> 4;
  int dtl = dt * 16 + lr;
  // hoist both phases' bin bounds (independent loads, overlap with qt MFMA below)
  int r0 = quarter * 2, r1 = r0 + 1;
  int binA = r0 * NN + dtl, binB = r1 * NN + dtl;
  int a0 = boff[binA], a1 = boff[binA + 1];
  int c0 = boff[binB], c1 = boff[binB + 1];
  const unsigned short* ap = qb + (size_t)dtl * 256 + h * 64 + kq * 8;
  bf16x8 aq0 = *(const bf16x8*)ap;
  bf16x8 aq1 = *(const bf16x8*)(ap + 32);
  f32x4 C[4] = {{0.f,0.f,0.f,0.f},{0.f,0.f,0.f,0.f},{0.f,0.f,0.f,0.f},{0.f,0.f,0.f,0.f}};
  float dtot = 0.f;
  for (int rr = 0; rr < 2; ++rr) {
    int r = r0 + rr;
    int rh = r * 4 + h;
    int b0 = rr ? c0 : a0, b1 = rr ? c1 : a1;
    // qt[dst, d] = sum_e q[dst,e] * A_r[h][d,e]  (MFMA; transpose via wave-private LDS)
#pragma unroll
    for (int tn = 0; tn < 4; ++tn) {
      const unsigned short* bp = Att + ((rh * 64 + tn * 16 + lr) * 64) + kq * 8;
      f32x4 acc = {0.f, 0.f, 0.f, 0.f};
      acc = mfma16(aq0, *(const bf16x8*)bp, acc);
      acc = mfma16(aq1, *(const bf16x8*)(bp + 32), acc);
#pragma unroll
      for (int i = 0; i < 4; ++i)
        qsh[h][kq * 4 + i][tn * 16 + lr] = f2bf(acc[i]);
    }
    float ql[8], qh[8];
#pragma unroll
    for (int m = 0; m < 8; ++m) ql[m] = bf2f(qsh[h][lr][kq * 8 + m]);
#pragma unroll
    for (int m = 0; m < 8; ++m) qh[m] = bf2f(qsh[h][lr][32 + kq * 8 + m]);
    float pscale = pri[rh] * 0.125f;
    float accl[8] = {0.f,0.f,0.f,0.f,0.f,0.f,0.f,0.f};
    float acch[8] = {0.f,0.f,0.f,0.f,0.f,0.f,0.f,0.f};
    float esum = 0.f;
    int j = b0;
    while (j + 2 <= b1) {
      int sA = je_src[j], sB = je_src[j + 1];
      const unsigned short* pA = kvb + (size_t)sA * 512 + h * 128 + kq * 8;
      const unsigned short* pB = kvb + (size_t)sB * 512 + h * 128 + kq * 8;
      bf16x8 kAl = *(const bf16x8*)pA,        kAh = *(const bf16x8*)(pA + 32);
      bf16x8 kBl = *(const bf16x8*)pB,        kBh = *(const bf16x8*)(pB + 32);
      bf16x8 vAl = *(const bf16x8*)(pA + 64), vAh = *(const bf16x8*)(pA + 96);
      bf16x8 vBl = *(const bf16x8*)(pB + 64), vBh = *(const bf16x8*)(pB + 96);
      float sa = 0.f, sb = 0.f;
#pragma unroll
      for (int m = 0; m < 8; ++m) {
        sa += ql[m] * bf2f((unsigned short)kAl[m]) + qh[m] * bf2f((unsigned short)kAh[m]);
        sb += ql[m] * bf2f((unsigned short)kBl[m]) + qh[m] * bf2f((unsigned short)kBh[m]);
      }
      sa += __shfl_xor(sa, 16); sa += __shfl_xor(sa, 32);
      sb += __shfl_xor(sb, 16); sb += __shfl_xor(sb, 32);
      float exA = __expf(sa * pscale), exB = __expf(sb * pscale);
      esum += exA + exB;
#pragma unroll
      for (int m = 0; m < 8; ++m) {
        accl[m] += exA * bf2f((unsigned short)vAl[m]) + exB * bf2f((unsigned short)vBl[m]);
        acch[m] += exA * bf2f((unsigned short)vAh[m]) + exB * bf2f((unsigned short)vBh[m]);
      }
      j += 2;
    }
    if (j < b1) {
      int sA = je_src[j];
      const unsigned short* pA = kvb + (size_t)sA * 512 + h * 128 + kq * 8;
      bf16x8 kAl = *(const bf16x8*)pA,        kAh = *(const bf16x8*)(pA + 32);
      bf16x8 vAl = *(const bf16x8*)(pA + 64), vAh = *(const bf16x8*)(pA + 96);
      float sa = 0.f;
#pragma unroll
      for (int m = 0; m < 8; ++m)
        sa += ql[m] * bf2f((unsigned short)kAl[m]) + qh[m] * bf2f((unsigned short)kAh[m]);
      sa += __shfl_xor(sa, 16); sa += __shfl_xor(sa, 32);
      float exA = __expf(sa * pscale);
      esum += exA;
#pragma unroll
      for (int m = 0; m < 8; ++m) {
        accl[m] += exA * bf2f((unsigned short)vAl[m]);
        acch[m] += exA * bf2f((unsigned short)vAh[m]);
      }
    }
    dtot += esum;
    bf16x8 m0, m1;
#pragma unroll
    for (int m = 0; m < 8; ++m) {
      m0[m] = (short)f2bf(accl[m]);
      m1[m] = (short)f2bf(acch[m]);
    }
#pragma unroll
    for (int tn = 0; tn < 4; ++tn) {
      const unsigned short* bp = Mt + ((rh * 64 + tn * 16 + lr) * 64) + kq * 8;
      C[tn] = mfma16(m0, *(const bf16x8*)bp, C[tn]);
      C[tn] = mfma16(m1, *(const bf16x8*)(bp + 32), C[tn]);
    }
  }
  if (kq == 0) atomicAdd(&denom[dtl * 4 + h], dtot);
#pragma unroll
  for (int tn = 0; tn < 4; ++tn)
#pragma unroll
    for (int i = 0; i < 4; ++i)
      aggh[((size_t)quarter * NN + dt * 16 + kq * 4 + i) * 256 + h * 64 + tn * 16 + lr] =
          f2bf(C[tn][i]);
}

// ---------------- K3: final typed projection + normalize + sigmoid(skip) ------------
__global__ __launch_bounds__(256) void k_gemm_out(
    const unsigned short* __restrict__ aggh, const float* __restrict__ denom,
    const unsigned short* __restrict__ At,
    const int* __restrict__ nperm, const int* __restrict__ toff,
    const int* __restrict__ mt_t, const int* __restrict__ mt_m,
    const int* __restrict__ gcnt,
    const float* __restrict__ skip, float* __restrict__ out) {
  int mtile = blockIdx.x;
  if (mtile >= gcnt[0]) return;
  int wave = threadIdx.x >> 6, lane = threadIdx.x & 63;
  int t = mt_t[mtile], tm = mt_m[mtile];
  int base = toff[t], cnt = toff[t + 1] - base;
  int lr = lane & 15, kq = lane >> 4;
  int arow = tm * 16 + lr;
  int prow = base + (arow < cnt ? arow : cnt - 1);
  float dn[4];
#pragma unroll
  for (int hh = 0; hh < 4; ++hh) {
    float d = denom[prow * 4 + hh];
    dn[hh] = d > 0.f ? 1.f / d : 0.f;
  }
  const unsigned short* g = aggh + (size_t)prow * 256 + kq * 8;
  bf16x8 af[8];
#pragma unroll
  for (int s = 0; s < 8; ++s) {
    bf16x8 x0 = *(const bf16x8*)(g + s * 32);
    bf16x8 x1 = *(const bf16x8*)(g + (size_t)NN * 256 + s * 32);
    bf16x8 x2 = *(const bf16x8*)(g + (size_t)2 * NN * 256 + s * 32);
    bf16x8 x3 = *(const bf16x8*)(g + (size_t)3 * NN * 256 + s * 32);
    float dv = dn[(kq * 8 + s * 32) >> 6];
#pragma unroll
    for (int m = 0; m < 8; ++m)
      af[s][m] = (short)f2bf((bf2f((unsigned short)x0[m]) + bf2f((unsigned short)x1[m]) +
                              bf2f((unsigned short)x2[m]) + bf2f((unsigned short)x3[m])) * dv);
  }
  int nd[4]; bool wr[4];
#pragma unroll
  for (int i = 0; i < 4; ++i) {
    int crow = tm * 16 + kq * 4 + i;
    wr[i] = crow < cnt;
    nd[i] = nperm[base + (wr[i] ? crow : 0)];
  }
  float sg = 1.f / (1.f + __expf(-skip[t]));
  for (int j = 0; j < 4; ++j) {
    int tn = wave * 4 + j;
    const unsigned short* bptr = At + (t * 256 + tn * 16 + lr) * 256 + kq * 8;
    f32x4 acc = {0.f, 0.f, 0.f, 0.f};
#pragma unroll
    for (int s = 0; s < 8; ++s)
      acc = mfma16(af[s], *(const bf16x8*)(bptr + s * 32), acc);
    int ccol = tn * 16 + lr;
#pragma unroll
    for (int i = 0; i < 4; ++i)
      if (wr[i]) out[nd[i] * 256 + ccol] = acc[i] * sg;
  }
}

extern "C" void kernel_launch(void* const* d_in, const int* in_sizes, int n_in,
                              void* d_out, int out_size, void* d_ws, size_t ws_size,
                              hipStream_t stream) {
  (void)in_sizes; (void)n_in; (void)out_size; (void)ws_size;
  const float* h    = (const float*)d_in[0];
  const float* Wk   = (const float*)d_in[1];
  const float* Wq   = (const float*)d_in[2];
  const float* Wv   = (const float*)d_in[3];
  const float* Wa   = (const float*)d_in[4];
  const float* ratt = (const float*)d_in[5];
  const float* rmsg = (const float*)d_in[6];
  const float* pri  = (const float*)d_in[7];
  const float* skp  = (const float*)d_in[8];
  const int* ntype  = (const int*)d_in[9];
  const int* etyp   = (const int*)d_in[10];
  const int* rowi   = (const int*)d_in[11];
  const int* coli   = (const int*)d_in[12];
  float* out = (float*)d_out;

  char* p = (char*)d_ws;
  auto alloc = [&](size_t bytes) {
    void* q = (void*)p;
    p += (bytes + 255) & ~(size_t)255;
    return q;
  };
  unsigned short* hbp  = (unsigned short*)alloc((size_t)NN * 256 * 2);
  unsigned short* Wt   = (unsigned short*)alloc((size_t)4 * 768 * 256 * 2);
  unsigned short* At   = (unsigned short*)alloc((size_t)4 * 256 * 256 * 2);
  unsigned short* Att  = (unsigned short*)alloc((size_t)32 * 4096 * 2);
  unsigned short* Mt   = (unsigned short*)alloc((size_t)32 * 4096 * 2);
  unsigned short* kvb  = (unsigned short*)alloc((size_t)NN * 512 * 2);
  unsigned short* qb   = (unsigned short*)alloc((size_t)NN * 256 * 2);
  unsigned short* aggh = (unsigned short*)alloc((size_t)4 * NN * 256 * 2);
  float* denom = (float*)alloc((size_t)NN * 4 * 4);
  int* toff  = (int*)alloc(32);
  int* ncur  = (int*)alloc(16);
  int* c4p   = (int*)alloc((size_t)CB * 4 * 4);
  int* nperm = (int*)alloc((size_t)NN * 4);
  int* inv   = (int*)alloc((size_t)NN * 4);
  int* bcnt  = (int*)alloc((size_t)NB * 4);
  int* boff  = (int*)alloc((size_t)(NB + 1) * 4);
  int* bcur  = (int*)alloc((size_t)NB * 4);
  int* psum  = (int*)alloc((size_t)625 * 4);
  int* je_src = (int*)alloc((size_t)NE * 4);
  int* mt_t = (int*)alloc((size_t)1253 * 4);
  int* mt_m = (int*)alloc((size_t)1253 * 4);
  int* gcnt = (int*)alloc(32);

  // node buckets (perm space)
  k_tcount<<<CB, 256, 0, stream>>>(ntype, c4p);
  k_meta<<<1, 256, 0, stream>>>(c4p, toff, ncur, mt_t, mt_m, gcnt);
  k_nscatter<<<CB, 256, 0, stream>>>(ntype, ncur, nperm, inv);

  // fused prep (zero + h-cast-perm + weight transposes)
  k_prep_all<<<ZB + HB + WB + AB + RB, 256, 0, stream>>>(
      h, Wk, Wq, Wv, Wa, ratt, rmsg, nperm, bcnt, denom, hbp, Wt, At, Att, Mt);

  // edge CSR by (rel, perm-dst)
  k_bcount<<<(NE + 255) / 256, 256, 0, stream>>>(etyp, coli, inv, bcnt);
  k_scan1<<<625, 256, 0, stream>>>(bcnt, boff, psum);
  k_scan2<<<1, 1024, 0, stream>>>(psum);
  k_scan3<<<625, 256, 0, stream>>>(boff, bcur, psum);
  k_escatter<<<(NE + 255) / 256, 256, 0, stream>>>(etyp, rowi, coli, inv, bcur, je_src);

  // main pipeline
  k_gemm_kqv<<<1253, 256, 0, stream>>>(hbp, Wt, toff, mt_t, mt_m, gcnt, kvb, qb);
  k_mega<<<5000, 256, 0, stream>>>(boff, je_src, qb, kvb, Att, Mt, pri, aggh, denom);
  k_gemm_out<<<1253, 256, 0, stream>>>(aggh, denom, At, nperm, toff, mt_t, mt_m, gcnt,
                                       skp, out);
}